// Round 8
// baseline (232.627 us; speedup 1.0000x reference)
//
#include <hip/hip_runtime.h>
#include <math.h>

#define BB 32
#define CC 256
#define NPIX 1024     // 32*32
#define KD 16
#define NHEADS 4
#define VDIM 64
#define RR 23
#define PADR 11
#define EPSBN 1e-5f
#define NCH 16        // lambda_c n-chunks per batch

typedef short short8v __attribute__((ext_vector_type(8)));
typedef short short4v __attribute__((ext_vector_type(4)));
typedef float floatx4 __attribute__((ext_vector_type(4)));

__device__ __forceinline__ unsigned short f2bf(float f) {
  union { float f; unsigned u; } c; c.f = f;
  unsigned u = c.u;
  return (unsigned short)((u + 0x7FFFu + ((u >> 16) & 1u)) >> 16);
}
__device__ __forceinline__ float bf2f(unsigned short h) {
  union { unsigned u; float f; } c; c.u = ((unsigned)h) << 16;
  return c.f;
}

// ---------------- K0: emb->bf16 A-layout  +  W pack (merged) ----------------
__global__ __launch_bounds__(256) void k_prep(const float* __restrict__ emb,
    unsigned short* __restrict__ embA,
    const float* __restrict__ Wq, const float* __restrict__ Wk,
    const float* __restrict__ Wv, unsigned short* __restrict__ wA) {
  int bid = blockIdx.x;
  if (bid < 46) {
    int l = bid * 256 + threadIdx.x;
    if (l >= 23 * 16 * 32) return;
    int dr = l >> 9, rem = l & 511;
    int m = rem >> 5, kd = rem & 31;
    unsigned short val = 0;
    if (kd < 23) val = f2bf(emb[(size_t)m * 529 + dr * 23 + kd]);
    embA[l] = val;
  } else {
    int idx = (bid - 46) * 256 + threadIdx.x;  // 0..36863
    int j = idx & 7, lane = (idx >> 3) & 63, ks = (idx >> 9) & 7, ot = idx >> 12;
    int o = ot * 16 + (lane & 15);
    int c = ks * 32 + (lane >> 4) * 8 + j;
    const float* src = (o < 64) ? (Wq + (size_t)o * CC)
                     : (o < 80) ? (Wk + (size_t)(o - 64) * CC)
                                : (Wv + (size_t)(o - 80) * CC);
    wA[idx] = f2bf(src[c]);
  }
}

// ---------------- K1: fused 144-channel 1x1-conv as bf16 MFMA GEMM ----------
__global__ __launch_bounds__(256) void k_proj(const float* __restrict__ x,
    const unsigned short* __restrict__ wA,
    float* __restrict__ q_pre, float* __restrict__ k_pre, float* __restrict__ v_pre) {
  int b = blockIdx.y;
  int t = threadIdx.x;
  int s = t >> 6;                 // wave id = 16-pixel subtile
  int lane = t & 63;
  int nl = lane & 15, quad = lane >> 4;
  int pix = blockIdx.x * 64 + s * 16 + nl;

  const float* xb = x + ((size_t)b * CC) * NPIX + pix;
  const unsigned short* ap = wA + lane * 8;

  floatx4 acc[9];
#pragma unroll
  for (int i = 0; i < 9; ++i) acc[i] = (floatx4){0.f, 0.f, 0.f, 0.f};

#pragma unroll
  for (int ks = 0; ks < 8; ++ks) {
    union { short8v v; unsigned short u[8]; } bb;
    const float* xc = xb + ((size_t)(ks * 32 + quad * 8)) * NPIX;
#pragma unroll
    for (int j = 0; j < 8; ++j) bb.u[j] = f2bf(xc[(size_t)j * NPIX]);
#pragma unroll
    for (int ot = 0; ot < 9; ++ot) {
      short8v af = *(const short8v*)(ap + ((ot * 8 + ks) << 9));
      acc[ot] = __builtin_amdgcn_mfma_f32_16x16x32_bf16(af, bb.v, acc[ot], 0, 0, 0);
    }
  }

#pragma unroll
  for (int ot = 0; ot < 9; ++ot) {
#pragma unroll
    for (int r = 0; r < 4; ++r) {
      int o = ot * 16 + quad * 4 + r;
      float val = acc[ot][r];
      if (o < 64)      q_pre[((size_t)b * 64 + o) * NPIX + pix] = val;
      else if (o < 80) k_pre[((size_t)b * 16 + (o - 64)) * NPIX + pix] = val;
      else             v_pre[((size_t)b * 64 + (o - 80)) * NPIX + pix] = val;
    }
  }
}

// ---------------- K2a: BN batch stats -> scale/shift ----------------
__global__ __launch_bounds__(256) void k_bnstats(const float* __restrict__ q_pre,
    const float* __restrict__ v_pre,
    const float* __restrict__ bn_q_w, const float* __restrict__ bn_q_b,
    const float* __restrict__ bn_v_w, const float* __restrict__ bn_v_b,
    float* __restrict__ stats) {
  int ch = blockIdx.x;            // 0..127
  bool isq = ch < 64;
  int c = isq ? ch : ch - 64;
  const float* src = (isq ? q_pre : v_pre) + (size_t)c * NPIX;
  float s = 0.f, ss = 0.f;
  for (int idx = threadIdx.x; idx < BB * NPIX; idx += 256) {
    int bb = idx >> 10, nn = idx & 1023;
    float v = src[(size_t)bb * 64 * NPIX + nn];
    s += v; ss = fmaf(v, v, ss);
  }
#pragma unroll
  for (int off = 32; off > 0; off >>= 1) {
    s += __shfl_down(s, off);
    ss += __shfl_down(ss, off);
  }
  __shared__ float sh[8];
  if ((threadIdx.x & 63) == 0) {
    sh[(threadIdx.x >> 6) * 2] = s;
    sh[(threadIdx.x >> 6) * 2 + 1] = ss;
  }
  __syncthreads();
  if (threadIdx.x == 0) {
    s = sh[0] + sh[2] + sh[4] + sh[6];
    ss = sh[1] + sh[3] + sh[5] + sh[7];
    const float inv = 1.0f / (float)(BB * NPIX);
    float mean = s * inv;
    float var = ss * inv - mean * mean;
    float rstd = rsqrtf(var + EPSBN);
    float w = isq ? bn_q_w[c] : bn_v_w[c];
    float bi = isq ? bn_q_b[c] : bn_v_b[c];
    float scale = rstd * w;
    float shift = bi - mean * scale;
    if (isq) { stats[c] = scale; stats[64 + c] = shift; }
    else     { stats[128 + c] = scale; stats[192 + c] = shift; }
  }
}

// ---------------- K2c: v-normalize+transpose  +  softmax (merged) -----------
__global__ __launch_bounds__(256) void k_nvsm(float* __restrict__ vn,
    const float* __restrict__ stats, float* __restrict__ vnT,
    const float* __restrict__ k_pre, float* __restrict__ p) {
  __shared__ float lds[64 * 65];
  __shared__ float shm[4], shs[4];
  int b = blockIdx.y, bx = blockIdx.x, t = threadIdx.x;
  if (bx < 16) {
    // ---- norm_v chunk bx ----
    int n0 = bx * 64;
    for (int l = t; l < 4096; l += 256) {
      int o = l >> 6, nn = l & 63;
      size_t a = ((size_t)b * 64 + o) * NPIX + n0 + nn;
      float v = fmaf(vn[a], stats[128 + o], stats[192 + o]);
      vn[a] = v;
      lds[o * 65 + nn] = v;
    }
    __syncthreads();
    for (int l = t; l < 4096; l += 256) {
      int nn = l >> 6, o = l & 63;
      vnT[((size_t)b * NPIX + n0 + nn) * 64 + o] = lds[o * 65 + nn];
    }
  } else {
    // ---- softmax k = bx-16 ----
    int k = bx - 16;
    const float* src = k_pre + ((size_t)b * 16 + k) * NPIX;
    float v[4];
    float mx = -1e30f;
#pragma unroll
    for (int i = 0; i < 4; ++i) { v[i] = src[t + 256 * i]; mx = fmaxf(mx, v[i]); }
#pragma unroll
    for (int off = 32; off > 0; off >>= 1) mx = fmaxf(mx, __shfl_down(mx, off));
    if ((t & 63) == 0) shm[t >> 6] = mx;
    __syncthreads();
    mx = fmaxf(fmaxf(shm[0], shm[1]), fmaxf(shm[2], shm[3]));
    float s = 0.f;
#pragma unroll
    for (int i = 0; i < 4; ++i) { v[i] = __expf(v[i] - mx); s += v[i]; }
#pragma unroll
    for (int off = 32; off > 0; off >>= 1) s += __shfl_down(s, off);
    if ((t & 63) == 0) shs[t >> 6] = s;
    __syncthreads();
    float r = 1.0f / (shs[0] + shs[1] + shs[2] + shs[3]);
    float* dst = p + ((size_t)b * 16 + k) * NPIX;
#pragma unroll
    for (int i = 0; i < 4; ++i) dst[t + 256 * i] = v[i] * r;
  }
}

// ---------------- K4 v2: chunked lambda_c partials ----------------
__global__ __launch_bounds__(256) void k_lambda_p(const float* __restrict__ p,
    const float* __restrict__ vnT, float* __restrict__ lcp) {
  __shared__ float pl[16 * 64];
  int b = blockIdx.y, nc = blockIdx.x, t = threadIdx.x;
  int n0 = nc * 64;
  for (int l = t; l < 1024; l += 256) {
    int k = l >> 6, nn = l & 63;
    pl[l] = p[((size_t)b * 16 + k) * NPIX + n0 + nn];
  }
  __syncthreads();
  int v = t & 63, wg = t >> 6;
  const float* vt = vnT + ((size_t)b * NPIX + n0) * 64 + v;
  float acc[4] = {0.f, 0.f, 0.f, 0.f};
  for (int i = 0; i < 64; ++i) {
    float val = vt[(size_t)i * 64];
#pragma unroll
    for (int j = 0; j < 4; ++j)
      acc[j] = fmaf(pl[(wg * 4 + j) * 64 + i], val, acc[j]);
  }
  float* dst = lcp + ((size_t)(b * NCH + nc) * 16) * 64;
#pragma unroll
  for (int j = 0; j < 4; ++j)
    dst[(size_t)(wg * 4 + j) * 64 + v] = acc[j];
}

// ---------------- shared LDS layout for conv kernel ----------------
#define IMG_RS 68            // shorts per padded row
#define IMG_CS (54 * IMG_RS) // shorts per copy = 3672
#define LAM_RS 1032          // lambda row stride in shorts (1024 + 8 pad)

union KMainLDS {
  short imgc[4 * IMG_CS];   // 29376 B
  short lam[16 * LAM_RS];   // 33024 B
};

__device__ __forceinline__ short8v ld_win(const short* p) {
  union { short8v s8; short4v s4[2]; } bu;
  bu.s4[0] = *(const short4v*)p;
  bu.s4[1] = *(const short4v*)(p + 4);
  return bu.s8;
}

// ---------------- K5a v2: MFMA conv, 8 waves x 4 rows (512 thr) --------------
// Same algorithm/layout as the passing 4-wave version; finer wave split:
// acc 8 tiles (32 reg) + bfrag ring 4 rows (32 reg) per thread -> ~2x waves/CU.
// Ring invariant: slot=(dr+rr)&3 holds row y0+dr+rr; refill row y0+dr+4 into
// slot dr&3 (needed next iter as rr=3: (dr+1+3)&3 = dr&3).
__global__ __launch_bounds__(512, 4) void k_conv(const float* __restrict__ vn,
    const float* __restrict__ lcp, const unsigned short* __restrict__ embA,
    unsigned short* __restrict__ lamG) {
  __shared__ __align__(16) KMainLDS u;
  __shared__ float lcv[16];
  int b = blockIdx.y, v = blockIdx.x, t = threadIdx.x;

  int4* z4 = (int4*)u.imgc;
  for (int l = t; l < 1836; l += 512) z4[l] = make_int4(0, 0, 0, 0);
  if (t < 16) {
    float s = 0.f;
#pragma unroll
    for (int nc = 0; nc < NCH; ++nc)
      s += lcp[(((size_t)b * NCH + nc) * 16 + t) * 64 + v];
    lcv[t] = s;
  }
  __syncthreads();

  const float* vsrc = vn + ((size_t)b * 64 + v) * NPIX;
  for (int l = t; l < 512; l += 512) {
    int pix = l * 2;
    int y = pix >> 5, xx = pix & 31;
    float2 vv = *(const float2*)(vsrc + pix);
    unsigned short h0 = f2bf(vv.x), h1 = f2bf(vv.y);
#pragma unroll
    for (int s = 0; s < 4; ++s) {
      int base = s * IMG_CS + (y + PADR) * IMG_RS + xx + PADR + s;
      u.imgc[base] = (short)h0;
      u.imgc[base + 1] = (short)h1;
    }
  }
  __syncthreads();

  int lane = t & 63, wv = t >> 6;   // wv 0..7
  int nl = lane & 15, quad = lane >> 4;
  int y0 = wv * 4;
  int scopy = (4 - (nl & 3)) & 3;
  int colbase = scopy * IMG_CS + nl + quad * 8 + scopy;
  const unsigned short* aptr = embA + nl * 32 + quad * 8;

  floatx4 acc[8];
#pragma unroll
  for (int i = 0; i < 8; ++i) acc[i] = (floatx4){0.f, 0.f, 0.f, 0.f};

  // prologue: cache rows y0..y0+3 (slot = row & 3)
  short8v bfrag[4][2];
#pragma unroll
  for (int rr = 0; rr < 4; ++rr) {
    const short* rp = &u.imgc[(y0 + rr) * IMG_RS + colbase];
    bfrag[rr][0] = ld_win(rp);
    bfrag[rr][1] = ld_win(rp + 16);
  }

  // depth-2 embA prefetch ring
  short8v a0 = *(const short8v*)aptr;
  short8v a1 = *(const short8v*)(aptr + 512);
#pragma unroll
  for (int dr = 0; dr < RR; ++dr) {
    short8v afrag = a0;
    a0 = a1;
    if (dr < RR - 2) a1 = *(const short8v*)(aptr + (dr + 2) * 512);
#pragma unroll
    for (int rr = 0; rr < 4; ++rr) {
      int slot = (dr + rr) & 3;
      acc[rr * 2 + 0] = __builtin_amdgcn_mfma_f32_16x16x32_bf16(afrag, bfrag[slot][0], acc[rr * 2 + 0], 0, 0, 0);
      acc[rr * 2 + 1] = __builtin_amdgcn_mfma_f32_16x16x32_bf16(afrag, bfrag[slot][1], acc[rr * 2 + 1], 0, 0, 0);
    }
    if (dr < RR - 1) {
      const short* rp = &u.imgc[(y0 + dr + 4) * IMG_RS + colbase];
      int slot = dr & 3;
      bfrag[slot][0] = ld_win(rp);
      bfrag[slot][1] = ld_win(rp + 16);
    }
  }

  __syncthreads();
#pragma unroll
  for (int tt = 0; tt < 8; ++tt) {
    int y = y0 + (tt >> 1), c0 = (tt & 1) << 4;
    int pix = y * 32 + c0 + nl;
#pragma unroll
    for (int r = 0; r < 4; ++r)
      u.lam[(quad * 4 + r) * LAM_RS + pix] = (short)f2bf(acc[tt][r] + lcv[quad * 4 + r]);
  }
  __syncthreads();

  // coalesced LDS -> global copy of lambda (16 rows x 1024 bf16 = 2048 uint4)
  uint4* dst = (uint4*)(lamG + ((size_t)(b * 64 + v)) * 16 * 1024);
  for (int idx = t; idx < 2048; idx += 512) {
    int row = idx >> 7, col = idx & 127;
    dst[row * 128 + col] = *(const uint4*)&u.lam[row * LAM_RS + col * 8];
  }
}

// ---------------- K5b v4: chunk-grid epilogue, z-split v-range ---------------
__global__ __launch_bounds__(256) void k_epi2(const unsigned short* __restrict__ lamG,
    const float* __restrict__ q_pre, const float* __restrict__ stats,
    const float* __restrict__ gamma, float* __restrict__ out) {
  __shared__ float qs[64 * 64];   // [o][n] 16 KB
  int b = blockIdx.y, nc = blockIdx.x, z = blockIdx.z, t = threadIdx.x;
  int n0 = nc * 64;
  for (int l = t; l < 4096; l += 256) {
    int o = l >> 6, nn = l & 63;
    qs[l] = fmaf(q_pre[((size_t)b * 64 + o) * NPIX + n0 + nn], stats[o], stats[64 + o]);
  }
  __syncthreads();
  float g1 = 1.0f + gamma[0];
  int p0 = (t & 15) * 4;
  int g = t >> 4;                 // 0..15
#pragma unroll
  for (int vi = 0; vi < 2; ++vi) {
    int v = z * 32 + vi * 16 + g;
    const unsigned short* ls = lamG + ((size_t)(b * 64 + v)) * 16 * 1024 + n0 + p0;
    float yacc[4][4];
#pragma unroll
    for (int h = 0; h < 4; ++h)
#pragma unroll
      for (int i = 0; i < 4; ++i) yacc[h][i] = 0.f;
#pragma unroll
    for (int k = 0; k < 16; ++k) {
      uint2 w = *(const uint2*)(ls + k * 1024);
      float l0 = bf2f((unsigned short)(w.x & 0xffffu));
      float l1 = bf2f((unsigned short)(w.x >> 16));
      float l2 = bf2f((unsigned short)(w.y & 0xffffu));
      float l3 = bf2f((unsigned short)(w.y >> 16));
#pragma unroll
      for (int h = 0; h < 4; ++h) {
        const float* qrow = &qs[(h * 16 + k) * 64 + p0];
        yacc[h][0] = fmaf(qrow[0], l0, yacc[h][0]);
        yacc[h][1] = fmaf(qrow[1], l1, yacc[h][1]);
        yacc[h][2] = fmaf(qrow[2], l2, yacc[h][2]);
        yacc[h][3] = fmaf(qrow[3], l3, yacc[h][3]);
      }
    }
#pragma unroll
    for (int h = 0; h < 4; ++h) {
      float4 r;
      r.x = g1 * yacc[h][0]; r.y = g1 * yacc[h][1];
      r.z = g1 * yacc[h][2]; r.w = g1 * yacc[h][3];
      *(float4*)&out[((size_t)b * 256 + h * 64 + v) * NPIX + n0 + p0] = r;
    }
  }
}

// ---------------- K5 fallback: fused conv+epilogue (known-passing R3) --------
__global__ __launch_bounds__(256, 3) void k_fused(const float* __restrict__ vn,
    const float* __restrict__ q_pre, const float* __restrict__ stats,
    const float* __restrict__ lcp, const unsigned short* __restrict__ embA,
    const float* __restrict__ gamma, float* __restrict__ out) {
  __shared__ __align__(16) KMainLDS u;
  __shared__ float lcv[16];
  int b = blockIdx.y, v = blockIdx.x, t = threadIdx.x;

  int4* z4 = (int4*)u.imgc;
  for (int l = t; l < 1836; l += 256) z4[l] = make_int4(0, 0, 0, 0);
  if (t < 16) {
    float s = 0.f;
#pragma unroll
    for (int nc = 0; nc < NCH; ++nc)
      s += lcp[(((size_t)b * NCH + nc) * 16 + t) * 64 + v];
    lcv[t] = s;
  }
  __syncthreads();

  const float* vsrc = vn + ((size_t)b * 64 + v) * NPIX;
  for (int l = t; l < 512; l += 256) {
    int pix = l * 2;
    int y = pix >> 5, xx = pix & 31;
    float2 vv = *(const float2*)(vsrc + pix);
    unsigned short h0 = f2bf(vv.x), h1 = f2bf(vv.y);
#pragma unroll
    for (int s = 0; s < 4; ++s) {
      int base = s * IMG_CS + (y + PADR) * IMG_RS + xx + PADR + s;
      u.imgc[base] = (short)h0;
      u.imgc[base + 1] = (short)h1;
    }
  }
  __syncthreads();

  int lane = t & 63, wv = t >> 6;
  int nl = lane & 15, quad = lane >> 4;
  int y0 = wv * 8;
  int scopy = (4 - (nl & 3)) & 3;
  int colbase = scopy * IMG_CS + nl + quad * 8 + scopy;
  const unsigned short* aptr = embA + nl * 32 + quad * 8;

  floatx4 acc[16];
#pragma unroll
  for (int i = 0; i < 16; ++i) acc[i] = (floatx4){0.f, 0.f, 0.f, 0.f};

  short8v bfrag[8][2];
#pragma unroll
  for (int rr = 0; rr < 8; ++rr) {
    const short* rp = &u.imgc[(y0 + rr) * IMG_RS + colbase];
    bfrag[rr][0] = ld_win(rp);
    bfrag[rr][1] = ld_win(rp + 16);
  }

  short8v a0 = *(const short8v*)aptr;
  short8v a1 = *(const short8v*)(aptr + 512);
#pragma unroll
  for (int dr = 0; dr < RR; ++dr) {
    short8v afrag = a0;
    a0 = a1;
    if (dr < RR - 2) a1 = *(const short8v*)(aptr + (dr + 2) * 512);
#pragma unroll
    for (int rr = 0; rr < 8; ++rr) {
      int slot = (dr + rr) & 7;
      acc[rr * 2 + 0] = __builtin_amdgcn_mfma_f32_16x16x32_bf16(afrag, bfrag[slot][0], acc[rr * 2 + 0], 0, 0, 0);
      acc[rr * 2 + 1] = __builtin_amdgcn_mfma_f32_16x16x32_bf16(afrag, bfrag[slot][1], acc[rr * 2 + 1], 0, 0, 0);
    }
    if (dr < RR - 1) {
      const short* rp = &u.imgc[(y0 + dr + 8) * IMG_RS + colbase];
      int slot = dr & 7;
      bfrag[slot][0] = ld_win(rp);
      bfrag[slot][1] = ld_win(rp + 16);
    }
  }

  __syncthreads();
#pragma unroll
  for (int tt = 0; tt < 16; ++tt) {
    int y = y0 + (tt >> 1), c0 = (tt & 1) << 4;
    int pix = y * 32 + c0 + nl;
#pragma unroll
    for (int r = 0; r < 4; ++r)
      u.lam[(quad * 4 + r) * LAM_RS + pix] = (short)f2bf(acc[tt][r] + lcv[quad * 4 + r]);
  }
  __syncthreads();

  int p0 = t * 4;
  float yacc[4][4];
#pragma unroll
  for (int h = 0; h < 4; ++h)
#pragma unroll
    for (int i = 0; i < 4; ++i) yacc[h][i] = 0.f;
  const float* qb = q_pre + ((size_t)b * 64) * NPIX + p0;
#pragma unroll
  for (int k = 0; k < 16; ++k) {
    uint2 w = *(const uint2*)&u.lam[k * LAM_RS + p0];
    float l0 = bf2f((unsigned short)(w.x & 0xffffu));
    float l1 = bf2f((unsigned short)(w.x >> 16));
    float l2 = bf2f((unsigned short)(w.y & 0xffffu));
    float l3 = bf2f((unsigned short)(w.y >> 16));
#pragma unroll
    for (int h = 0; h < 4; ++h) {
      int o = h * 16 + k;
      float4 qv = *(const float4*)(qb + (size_t)o * NPIX);
      float s = stats[o], sh = stats[64 + o];
      yacc[h][0] = fmaf(fmaf(qv.x, s, sh), l0, yacc[h][0]);
      yacc[h][1] = fmaf(fmaf(qv.y, s, sh), l1, yacc[h][1]);
      yacc[h][2] = fmaf(fmaf(qv.z, s, sh), l2, yacc[h][2]);
      yacc[h][3] = fmaf(fmaf(qv.w, s, sh), l3, yacc[h][3]);
    }
  }
  float g1 = 1.0f + gamma[0];
#pragma unroll
  for (int h = 0; h < 4; ++h) {
    float4 r;
    r.x = g1 * yacc[h][0]; r.y = g1 * yacc[h][1];
    r.z = g1 * yacc[h][2]; r.w = g1 * yacc[h][3];
    *(float4*)&out[((size_t)b * 256 + h * 64 + v) * NPIX + p0] = r;
  }
}

extern "C" void kernel_launch(void* const* d_in, const int* in_sizes, int n_in,
                              void* d_out, int out_size, void* d_ws, size_t ws_size,
                              hipStream_t stream) {
  const float* x      = (const float*)d_in[0];
  const float* Wq     = (const float*)d_in[1];
  const float* bn_q_w = (const float*)d_in[2];
  const float* bn_q_b = (const float*)d_in[3];
  const float* Wk     = (const float*)d_in[4];
  const float* Wv     = (const float*)d_in[5];
  const float* bn_v_w = (const float*)d_in[6];
  const float* bn_v_b = (const float*)d_in[7];
  const float* emb    = (const float*)d_in[8];
  const float* gamma  = (const float*)d_in[9];
  float* out = (float*)d_out;

  float* ws    = (float*)d_ws;
  float* q_pre = ws;                                     // B*64*N
  float* k_pre = q_pre + (size_t)BB * 64 * NPIX;         // B*16*N
  float* vn    = k_pre + (size_t)BB * 16 * NPIX;         // B*64*N
  float* vnT   = vn    + (size_t)BB * 64 * NPIX;         // B*N*64
  float* p     = vnT   + (size_t)BB * NPIX * 64;         // B*16*N
  float* lcp   = p     + (size_t)BB * 16 * NPIX;         // B*NCH*16*64
  float* stats = lcp   + (size_t)BB * NCH * 16 * 64;     // 256
  unsigned short* embA = (unsigned short*)(stats + 256); // 23*16*32 ushorts
  unsigned short* wA   = embA + 23 * 16 * 32;            // 144*256 ushorts
  unsigned short* lamG = wA + 144 * 256;                 // B*64*16*N ushorts (64 MB)

  size_t need = ((size_t)(lamG - (unsigned short*)ws)) * 2
              + (size_t)BB * 64 * 16 * NPIX * 2;

  k_prep    <<<dim3(190),     256, 0, stream>>>(emb, embA, Wq, Wk, Wv, wA);
  k_proj    <<<dim3(16, BB),  256, 0, stream>>>(x, wA, q_pre, k_pre, vn);
  k_bnstats <<<dim3(128),     256, 0, stream>>>(q_pre, vn, bn_q_w, bn_q_b, bn_v_w, bn_v_b, stats);
  k_nvsm    <<<dim3(32, BB),  256, 0, stream>>>(vn, stats, vnT, k_pre, p);
  k_lambda_p<<<dim3(NCH, BB), 256, 0, stream>>>(p, vnT, lcp);
  if (ws_size >= need) {
    k_conv  <<<dim3(64, BB),    512, 0, stream>>>(vn, lcp, embA, lamG);
    k_epi2  <<<dim3(16, BB, 2), 256, 0, stream>>>(lamG, q_pre, stats, gamma, out);
  } else {
    k_fused <<<dim3(64, BB),    256, 0, stream>>>(vn, q_pre, stats, lcp, embA, gamma, out);
  }
}

// Round 9
// 228.742 us; speedup vs baseline: 1.0170x; 1.0170x over previous
//
#include <hip/hip_runtime.h>
#include <math.h>

#define BB 32
#define CC 256
#define NPIX 1024     // 32*32
#define KD 16
#define NHEADS 4
#define VDIM 64
#define RR 23
#define PADR 11
#define EPSBN 1e-5f
#define NCH 16        // lambda_c n-chunks per batch

typedef short short8v __attribute__((ext_vector_type(8)));
typedef short short4v __attribute__((ext_vector_type(4)));
typedef float floatx4 __attribute__((ext_vector_type(4)));

__device__ __forceinline__ unsigned short f2bf(float f) {
  union { float f; unsigned u; } c; c.f = f;
  unsigned u = c.u;
  return (unsigned short)((u + 0x7FFFu + ((u >> 16) & 1u)) >> 16);
}
__device__ __forceinline__ float bf2f(unsigned short h) {
  union { unsigned u; float f; } c; c.u = ((unsigned)h) << 16;
  return c.f;
}

// ---------------- K0: emb->bf16 A-layout  +  W pack (merged) ----------------
__global__ __launch_bounds__(256) void k_prep(const float* __restrict__ emb,
    unsigned short* __restrict__ embA,
    const float* __restrict__ Wq, const float* __restrict__ Wk,
    const float* __restrict__ Wv, unsigned short* __restrict__ wA) {
  int bid = blockIdx.x;
  if (bid < 46) {
    int l = bid * 256 + threadIdx.x;
    if (l >= 23 * 16 * 32) return;
    int dr = l >> 9, rem = l & 511;
    int m = rem >> 5, kd = rem & 31;
    unsigned short val = 0;
    if (kd < 23) val = f2bf(emb[(size_t)m * 529 + dr * 23 + kd]);
    embA[l] = val;
  } else {
    int idx = (bid - 46) * 256 + threadIdx.x;  // 0..36863
    int j = idx & 7, lane = (idx >> 3) & 63, ks = (idx >> 9) & 7, ot = idx >> 12;
    int o = ot * 16 + (lane & 15);
    int c = ks * 32 + (lane >> 4) * 8 + j;
    const float* src = (o < 64) ? (Wq + (size_t)o * CC)
                     : (o < 80) ? (Wk + (size_t)(o - 64) * CC)
                                : (Wv + (size_t)(o - 80) * CC);
    wA[idx] = f2bf(src[c]);
  }
}

// ---------------- K1: fused 144-channel 1x1-conv as bf16 MFMA GEMM ----------
__global__ __launch_bounds__(256) void k_proj(const float* __restrict__ x,
    const unsigned short* __restrict__ wA,
    float* __restrict__ q_pre, float* __restrict__ k_pre, float* __restrict__ v_pre) {
  int b = blockIdx.y;
  int t = threadIdx.x;
  int s = t >> 6;                 // wave id = 16-pixel subtile
  int lane = t & 63;
  int nl = lane & 15, quad = lane >> 4;
  int pix = blockIdx.x * 64 + s * 16 + nl;

  const float* xb = x + ((size_t)b * CC) * NPIX + pix;
  const unsigned short* ap = wA + lane * 8;

  floatx4 acc[9];
#pragma unroll
  for (int i = 0; i < 9; ++i) acc[i] = (floatx4){0.f, 0.f, 0.f, 0.f};

#pragma unroll
  for (int ks = 0; ks < 8; ++ks) {
    union { short8v v; unsigned short u[8]; } bb;
    const float* xc = xb + ((size_t)(ks * 32 + quad * 8)) * NPIX;
#pragma unroll
    for (int j = 0; j < 8; ++j) bb.u[j] = f2bf(xc[(size_t)j * NPIX]);
#pragma unroll
    for (int ot = 0; ot < 9; ++ot) {
      short8v af = *(const short8v*)(ap + ((ot * 8 + ks) << 9));
      acc[ot] = __builtin_amdgcn_mfma_f32_16x16x32_bf16(af, bb.v, acc[ot], 0, 0, 0);
    }
  }

#pragma unroll
  for (int ot = 0; ot < 9; ++ot) {
#pragma unroll
    for (int r = 0; r < 4; ++r) {
      int o = ot * 16 + quad * 4 + r;
      float val = acc[ot][r];
      if (o < 64)      q_pre[((size_t)b * 64 + o) * NPIX + pix] = val;
      else if (o < 80) k_pre[((size_t)b * 16 + (o - 64)) * NPIX + pix] = val;
      else             v_pre[((size_t)b * 64 + (o - 80)) * NPIX + pix] = val;
    }
  }
}

// ---------------- K2a: BN batch stats -> scale/shift ----------------
__global__ __launch_bounds__(256) void k_bnstats(const float* __restrict__ q_pre,
    const float* __restrict__ v_pre,
    const float* __restrict__ bn_q_w, const float* __restrict__ bn_q_b,
    const float* __restrict__ bn_v_w, const float* __restrict__ bn_v_b,
    float* __restrict__ stats) {
  int ch = blockIdx.x;            // 0..127
  bool isq = ch < 64;
  int c = isq ? ch : ch - 64;
  const float* src = (isq ? q_pre : v_pre) + (size_t)c * NPIX;
  float s = 0.f, ss = 0.f;
  for (int idx = threadIdx.x; idx < BB * NPIX; idx += 256) {
    int bb = idx >> 10, nn = idx & 1023;
    float v = src[(size_t)bb * 64 * NPIX + nn];
    s += v; ss = fmaf(v, v, ss);
  }
#pragma unroll
  for (int off = 32; off > 0; off >>= 1) {
    s += __shfl_down(s, off);
    ss += __shfl_down(ss, off);
  }
  __shared__ float sh[8];
  if ((threadIdx.x & 63) == 0) {
    sh[(threadIdx.x >> 6) * 2] = s;
    sh[(threadIdx.x >> 6) * 2 + 1] = ss;
  }
  __syncthreads();
  if (threadIdx.x == 0) {
    s = sh[0] + sh[2] + sh[4] + sh[6];
    ss = sh[1] + sh[3] + sh[5] + sh[7];
    const float inv = 1.0f / (float)(BB * NPIX);
    float mean = s * inv;
    float var = ss * inv - mean * mean;
    float rstd = rsqrtf(var + EPSBN);
    float w = isq ? bn_q_w[c] : bn_v_w[c];
    float bi = isq ? bn_q_b[c] : bn_v_b[c];
    float scale = rstd * w;
    float shift = bi - mean * scale;
    if (isq) { stats[c] = scale; stats[64 + c] = shift; }
    else     { stats[128 + c] = scale; stats[192 + c] = shift; }
  }
}

// ---------------- K2c: v-normalize+transpose  +  softmax (merged) -----------
__global__ __launch_bounds__(256) void k_nvsm(float* __restrict__ vn,
    const float* __restrict__ stats, float* __restrict__ vnT,
    const float* __restrict__ k_pre, float* __restrict__ p) {
  __shared__ float lds[64 * 65];
  __shared__ float shm[4], shs[4];
  int b = blockIdx.y, bx = blockIdx.x, t = threadIdx.x;
  if (bx < 16) {
    // ---- norm_v chunk bx ----
    int n0 = bx * 64;
    for (int l = t; l < 4096; l += 256) {
      int o = l >> 6, nn = l & 63;
      size_t a = ((size_t)b * 64 + o) * NPIX + n0 + nn;
      float v = fmaf(vn[a], stats[128 + o], stats[192 + o]);
      vn[a] = v;
      lds[o * 65 + nn] = v;
    }
    __syncthreads();
    for (int l = t; l < 4096; l += 256) {
      int nn = l >> 6, o = l & 63;
      vnT[((size_t)b * NPIX + n0 + nn) * 64 + o] = lds[o * 65 + nn];
    }
  } else {
    // ---- softmax k = bx-16 ----
    int k = bx - 16;
    const float* src = k_pre + ((size_t)b * 16 + k) * NPIX;
    float v[4];
    float mx = -1e30f;
#pragma unroll
    for (int i = 0; i < 4; ++i) { v[i] = src[t + 256 * i]; mx = fmaxf(mx, v[i]); }
#pragma unroll
    for (int off = 32; off > 0; off >>= 1) mx = fmaxf(mx, __shfl_down(mx, off));
    if ((t & 63) == 0) shm[t >> 6] = mx;
    __syncthreads();
    mx = fmaxf(fmaxf(shm[0], shm[1]), fmaxf(shm[2], shm[3]));
    float s = 0.f;
#pragma unroll
    for (int i = 0; i < 4; ++i) { v[i] = __expf(v[i] - mx); s += v[i]; }
#pragma unroll
    for (int off = 32; off > 0; off >>= 1) s += __shfl_down(s, off);
    if ((t & 63) == 0) shs[t >> 6] = s;
    __syncthreads();
    float r = 1.0f / (shs[0] + shs[1] + shs[2] + shs[3]);
    float* dst = p + ((size_t)b * 16 + k) * NPIX;
#pragma unroll
    for (int i = 0; i < 4; ++i) dst[t + 256 * i] = v[i] * r;
  }
}

// ---------------- K4 v2: chunked lambda_c partials ----------------
__global__ __launch_bounds__(256) void k_lambda_p(const float* __restrict__ p,
    const float* __restrict__ vnT, float* __restrict__ lcp) {
  __shared__ float pl[16 * 64];
  int b = blockIdx.y, nc = blockIdx.x, t = threadIdx.x;
  int n0 = nc * 64;
  for (int l = t; l < 1024; l += 256) {
    int k = l >> 6, nn = l & 63;
    pl[l] = p[((size_t)b * 16 + k) * NPIX + n0 + nn];
  }
  __syncthreads();
  int v = t & 63, wg = t >> 6;
  const float* vt = vnT + ((size_t)b * NPIX + n0) * 64 + v;
  float acc[4] = {0.f, 0.f, 0.f, 0.f};
  for (int i = 0; i < 64; ++i) {
    float val = vt[(size_t)i * 64];
#pragma unroll
    for (int j = 0; j < 4; ++j)
      acc[j] = fmaf(pl[(wg * 4 + j) * 64 + i], val, acc[j]);
  }
  float* dst = lcp + ((size_t)(b * NCH + nc) * 16) * 64;
#pragma unroll
  for (int j = 0; j < 4; ++j)
    dst[(size_t)(wg * 4 + j) * 64 + v] = acc[j];
}

// ---------------- shared LDS layout for conv kernel ----------------
// IMG_CS = 3728 shorts = 1864 dwords == 8 (mod 32): copy-to-copy bank shift
// 8*scopy spreads the sheared 8B ld_win reads to 15/16 distinct bank-pairs
// (old 3672 == 12 mod 32 gave 2 dups + 4-bank hole -> ~4-way conflicts).
#define IMG_RS 68            // shorts per padded row
#define IMG_CS 3728          // shorts per copy (54*68=3672 used + 56 pad)
#define LAM_RS 1032          // lambda row stride in shorts (1024 + 8 pad)

union KMainLDS {
  short imgc[4 * IMG_CS];   // 29824 B
  short lam[16 * LAM_RS];   // 33024 B
};

__device__ __forceinline__ short8v ld_win(const short* p) {
  union { short8v s8; short4v s4[2]; } bu;
  bu.s4[0] = *(const short4v*)p;
  bu.s4[1] = *(const short4v*)(p + 4);
  return bu.s8;
}

// ---------------- K5a: MFMA conv (4 waves x 8 rows, rolling B-frag cache) ----
__global__ __launch_bounds__(256, 3) void k_conv(const float* __restrict__ vn,
    const float* __restrict__ lcp, const unsigned short* __restrict__ embA,
    unsigned short* __restrict__ lamG) {
  __shared__ __align__(16) KMainLDS u;
  __shared__ float lcv[16];
  int b = blockIdx.y, v = blockIdx.x, t = threadIdx.x;

  int4* z4 = (int4*)u.imgc;
  for (int l = t; l < 1864; l += 256) z4[l] = make_int4(0, 0, 0, 0);
  if (t < 16) {
    float s = 0.f;
#pragma unroll
    for (int nc = 0; nc < NCH; ++nc)
      s += lcp[(((size_t)b * NCH + nc) * 16 + t) * 64 + v];
    lcv[t] = s;
  }
  __syncthreads();

  const float* vsrc = vn + ((size_t)b * 64 + v) * NPIX;
  for (int l = t; l < 512; l += 256) {
    int pix = l * 2;
    int y = pix >> 5, xx = pix & 31;
    float2 vv = *(const float2*)(vsrc + pix);
    unsigned short h0 = f2bf(vv.x), h1 = f2bf(vv.y);
#pragma unroll
    for (int s = 0; s < 4; ++s) {
      int base = s * IMG_CS + (y + PADR) * IMG_RS + xx + PADR + s;
      u.imgc[base] = (short)h0;
      u.imgc[base + 1] = (short)h1;
    }
  }
  __syncthreads();

  int lane = t & 63, wv = t >> 6;
  int nl = lane & 15, quad = lane >> 4;
  int y0 = wv * 8;
  int scopy = (4 - (nl & 3)) & 3;
  int colbase = scopy * IMG_CS + nl + quad * 8 + scopy;
  const unsigned short* aptr = embA + nl * 32 + quad * 8;

  floatx4 acc[16];
#pragma unroll
  for (int i = 0; i < 16; ++i) acc[i] = (floatx4){0.f, 0.f, 0.f, 0.f};

  // prologue: cache rows y0..y0+7 (slot = row & 7)
  short8v bfrag[8][2];
#pragma unroll
  for (int rr = 0; rr < 8; ++rr) {
    const short* rp = &u.imgc[(y0 + rr) * IMG_RS + colbase];
    bfrag[rr][0] = ld_win(rp);
    bfrag[rr][1] = ld_win(rp + 16);
  }

  // depth-2 embA prefetch ring
  short8v a0 = *(const short8v*)aptr;
  short8v a1 = *(const short8v*)(aptr + 512);
#pragma unroll
  for (int dr = 0; dr < RR; ++dr) {
    short8v afrag = a0;
    a0 = a1;
    if (dr < RR - 2) a1 = *(const short8v*)(aptr + (dr + 2) * 512);
#pragma unroll
    for (int rr = 0; rr < 8; ++rr) {
      int slot = (dr + rr) & 7;
      acc[rr * 2 + 0] = __builtin_amdgcn_mfma_f32_16x16x32_bf16(afrag, bfrag[slot][0], acc[rr * 2 + 0], 0, 0, 0);
      acc[rr * 2 + 1] = __builtin_amdgcn_mfma_f32_16x16x32_bf16(afrag, bfrag[slot][1], acc[rr * 2 + 1], 0, 0, 0);
    }
    if (dr < RR - 1) {
      const short* rp = &u.imgc[(y0 + dr + 8) * IMG_RS + colbase];
      int slot = dr & 7;
      bfrag[slot][0] = ld_win(rp);
      bfrag[slot][1] = ld_win(rp + 16);
    }
  }

  __syncthreads();
#pragma unroll
  for (int tt = 0; tt < 16; ++tt) {
    int y = y0 + (tt >> 1), c0 = (tt & 1) << 4;
    int pix = y * 32 + c0 + nl;
#pragma unroll
    for (int r = 0; r < 4; ++r)
      u.lam[(quad * 4 + r) * LAM_RS + pix] = (short)f2bf(acc[tt][r] + lcv[quad * 4 + r]);
  }
  __syncthreads();

  // coalesced LDS -> global copy of lambda (16 rows x 1024 bf16 = 2048 uint4)
  uint4* dst = (uint4*)(lamG + ((size_t)(b * 64 + v)) * 16 * 1024);
  for (int idx = t; idx < 2048; idx += 256) {
    int row = idx >> 7, col = idx & 127;
    dst[row * 128 + col] = *(const uint4*)&u.lam[row * LAM_RS + col * 8];
  }
}

// ---------------- K5b v4: chunk-grid epilogue, z-split v-range ---------------
__global__ __launch_bounds__(256) void k_epi2(const unsigned short* __restrict__ lamG,
    const float* __restrict__ q_pre, const float* __restrict__ stats,
    const float* __restrict__ gamma, float* __restrict__ out) {
  __shared__ float qs[64 * 64];   // [o][n] 16 KB
  int b = blockIdx.y, nc = blockIdx.x, z = blockIdx.z, t = threadIdx.x;
  int n0 = nc * 64;
  for (int l = t; l < 4096; l += 256) {
    int o = l >> 6, nn = l & 63;
    qs[l] = fmaf(q_pre[((size_t)b * 64 + o) * NPIX + n0 + nn], stats[o], stats[64 + o]);
  }
  __syncthreads();
  float g1 = 1.0f + gamma[0];
  int p0 = (t & 15) * 4;
  int g = t >> 4;                 // 0..15
#pragma unroll
  for (int vi = 0; vi < 2; ++vi) {
    int v = z * 32 + vi * 16 + g;
    const unsigned short* ls = lamG + ((size_t)(b * 64 + v)) * 16 * 1024 + n0 + p0;
    float yacc[4][4];
#pragma unroll
    for (int h = 0; h < 4; ++h)
#pragma unroll
      for (int i = 0; i < 4; ++i) yacc[h][i] = 0.f;
#pragma unroll
    for (int k = 0; k < 16; ++k) {
      uint2 w = *(const uint2*)(ls + k * 1024);
      float l0 = bf2f((unsigned short)(w.x & 0xffffu));
      float l1 = bf2f((unsigned short)(w.x >> 16));
      float l2 = bf2f((unsigned short)(w.y & 0xffffu));
      float l3 = bf2f((unsigned short)(w.y >> 16));
#pragma unroll
      for (int h = 0; h < 4; ++h) {
        const float* qrow = &qs[(h * 16 + k) * 64 + p0];
        yacc[h][0] = fmaf(qrow[0], l0, yacc[h][0]);
        yacc[h][1] = fmaf(qrow[1], l1, yacc[h][1]);
        yacc[h][2] = fmaf(qrow[2], l2, yacc[h][2]);
        yacc[h][3] = fmaf(qrow[3], l3, yacc[h][3]);
      }
    }
#pragma unroll
    for (int h = 0; h < 4; ++h) {
      float4 r;
      r.x = g1 * yacc[h][0]; r.y = g1 * yacc[h][1];
      r.z = g1 * yacc[h][2]; r.w = g1 * yacc[h][3];
      *(float4*)&out[((size_t)b * 256 + h * 64 + v) * NPIX + n0 + p0] = r;
    }
  }
}

// ---------------- K5 fallback: fused conv+epilogue (known-passing R3) --------
__global__ __launch_bounds__(256, 3) void k_fused(const float* __restrict__ vn,
    const float* __restrict__ q_pre, const float* __restrict__ stats,
    const float* __restrict__ lcp, const unsigned short* __restrict__ embA,
    const float* __restrict__ gamma, float* __restrict__ out) {
  __shared__ __align__(16) KMainLDS u;
  __shared__ float lcv[16];
  int b = blockIdx.y, v = blockIdx.x, t = threadIdx.x;

  int4* z4 = (int4*)u.imgc;
  for (int l = t; l < 1864; l += 256) z4[l] = make_int4(0, 0, 0, 0);
  if (t < 16) {
    float s = 0.f;
#pragma unroll
    for (int nc = 0; nc < NCH; ++nc)
      s += lcp[(((size_t)b * NCH + nc) * 16 + t) * 64 + v];
    lcv[t] = s;
  }
  __syncthreads();

  const float* vsrc = vn + ((size_t)b * 64 + v) * NPIX;
  for (int l = t; l < 512; l += 256) {
    int pix = l * 2;
    int y = pix >> 5, xx = pix & 31;
    float2 vv = *(const float2*)(vsrc + pix);
    unsigned short h0 = f2bf(vv.x), h1 = f2bf(vv.y);
#pragma unroll
    for (int s = 0; s < 4; ++s) {
      int base = s * IMG_CS + (y + PADR) * IMG_RS + xx + PADR + s;
      u.imgc[base] = (short)h0;
      u.imgc[base + 1] = (short)h1;
    }
  }
  __syncthreads();

  int lane = t & 63, wv = t >> 6;
  int nl = lane & 15, quad = lane >> 4;
  int y0 = wv * 8;
  int scopy = (4 - (nl & 3)) & 3;
  int colbase = scopy * IMG_CS + nl + quad * 8 + scopy;
  const unsigned short* aptr = embA + nl * 32 + quad * 8;

  floatx4 acc[16];
#pragma unroll
  for (int i = 0; i < 16; ++i) acc[i] = (floatx4){0.f, 0.f, 0.f, 0.f};

  short8v bfrag[8][2];
#pragma unroll
  for (int rr = 0; rr < 8; ++rr) {
    const short* rp = &u.imgc[(y0 + rr) * IMG_RS + colbase];
    bfrag[rr][0] = ld_win(rp);
    bfrag[rr][1] = ld_win(rp + 16);
  }

  short8v a0 = *(const short8v*)aptr;
  short8v a1 = *(const short8v*)(aptr + 512);
#pragma unroll
  for (int dr = 0; dr < RR; ++dr) {
    short8v afrag = a0;
    a0 = a1;
    if (dr < RR - 2) a1 = *(const short8v*)(aptr + (dr + 2) * 512);
#pragma unroll
    for (int rr = 0; rr < 8; ++rr) {
      int slot = (dr + rr) & 7;
      acc[rr * 2 + 0] = __builtin_amdgcn_mfma_f32_16x16x32_bf16(afrag, bfrag[slot][0], acc[rr * 2 + 0], 0, 0, 0);
      acc[rr * 2 + 1] = __builtin_amdgcn_mfma_f32_16x16x32_bf16(afrag, bfrag[slot][1], acc[rr * 2 + 1], 0, 0, 0);
    }
    if (dr < RR - 1) {
      const short* rp = &u.imgc[(y0 + dr + 8) * IMG_RS + colbase];
      int slot = dr & 7;
      bfrag[slot][0] = ld_win(rp);
      bfrag[slot][1] = ld_win(rp + 16);
    }
  }

  __syncthreads();
#pragma unroll
  for (int tt = 0; tt < 16; ++tt) {
    int y = y0 + (tt >> 1), c0 = (tt & 1) << 4;
    int pix = y * 32 + c0 + nl;
#pragma unroll
    for (int r = 0; r < 4; ++r)
      u.lam[(quad * 4 + r) * LAM_RS + pix] = (short)f2bf(acc[tt][r] + lcv[quad * 4 + r]);
  }
  __syncthreads();

  int p0 = t * 4;
  float yacc[4][4];
#pragma unroll
  for (int h = 0; h < 4; ++h)
#pragma unroll
    for (int i = 0; i < 4; ++i) yacc[h][i] = 0.f;
  const float* qb = q_pre + ((size_t)b * 64) * NPIX + p0;
#pragma unroll
  for (int k = 0; k < 16; ++k) {
    uint2 w = *(const uint2*)&u.lam[k * LAM_RS + p0];
    float l0 = bf2f((unsigned short)(w.x & 0xffffu));
    float l1 = bf2f((unsigned short)(w.x >> 16));
    float l2 = bf2f((unsigned short)(w.y & 0xffffu));
    float l3 = bf2f((unsigned short)(w.y >> 16));
#pragma unroll
    for (int h = 0; h < 4; ++h) {
      int o = h * 16 + k;
      float4 qv = *(const float4*)(qb + (size_t)o * NPIX);
      float s = stats[o], sh = stats[64 + o];
      yacc[h][0] = fmaf(fmaf(qv.x, s, sh), l0, yacc[h][0]);
      yacc[h][1] = fmaf(fmaf(qv.y, s, sh), l1, yacc[h][1]);
      yacc[h][2] = fmaf(fmaf(qv.z, s, sh), l2, yacc[h][2]);
      yacc[h][3] = fmaf(fmaf(qv.w, s, sh), l3, yacc[h][3]);
    }
  }
  float g1 = 1.0f + gamma[0];
#pragma unroll
  for (int h = 0; h < 4; ++h) {
    float4 r;
    r.x = g1 * yacc[h][0]; r.y = g1 * yacc[h][1];
    r.z = g1 * yacc[h][2]; r.w = g1 * yacc[h][3];
    *(float4*)&out[((size_t)b * 256 + h * 64 + v) * NPIX + p0] = r;
  }
}

extern "C" void kernel_launch(void* const* d_in, const int* in_sizes, int n_in,
                              void* d_out, int out_size, void* d_ws, size_t ws_size,
                              hipStream_t stream) {
  const float* x      = (const float*)d_in[0];
  const float* Wq     = (const float*)d_in[1];
  const float* bn_q_w = (const float*)d_in[2];
  const float* bn_q_b = (const float*)d_in[3];
  const float* Wk     = (const float*)d_in[4];
  const float* Wv     = (const float*)d_in[5];
  const float* bn_v_w = (const float*)d_in[6];
  const float* bn_v_b = (const float*)d_in[7];
  const float* emb    = (const float*)d_in[8];
  const float* gamma  = (const float*)d_in[9];
  float* out = (float*)d_out;

  float* ws    = (float*)d_ws;
  float* q_pre = ws;                                     // B*64*N
  float* k_pre = q_pre + (size_t)BB * 64 * NPIX;         // B*16*N
  float* vn    = k_pre + (size_t)BB * 16 * NPIX;         // B*64*N
  float* vnT   = vn    + (size_t)BB * 64 * NPIX;         // B*N*64
  float* p     = vnT   + (size_t)BB * NPIX * 64;         // B*16*N
  float* lcp   = p     + (size_t)BB * 16 * NPIX;         // B*NCH*16*64
  float* stats = lcp   + (size_t)BB * NCH * 16 * 64;     // 256
  unsigned short* embA = (unsigned short*)(stats + 256); // 23*16*32 ushorts
  unsigned short* wA   = embA + 23 * 16 * 32;            // 144*256 ushorts
  unsigned short* lamG = wA + 144 * 256;                 // B*64*16*N ushorts (64 MB)

  size_t need = ((size_t)(lamG - (unsigned short*)ws)) * 2
              + (size_t)BB * 64 * 16 * NPIX * 2;

  k_prep    <<<dim3(190),     256, 0, stream>>>(emb, embA, Wq, Wk, Wv, wA);
  k_proj    <<<dim3(16, BB),  256, 0, stream>>>(x, wA, q_pre, k_pre, vn);
  k_bnstats <<<dim3(128),     256, 0, stream>>>(q_pre, vn, bn_q_w, bn_q_b, bn_v_w, bn_v_b, stats);
  k_nvsm    <<<dim3(32, BB),  256, 0, stream>>>(vn, stats, vnT, k_pre, p);
  k_lambda_p<<<dim3(NCH, BB), 256, 0, stream>>>(p, vnT, lcp);
  if (ws_size >= need) {
    k_conv  <<<dim3(64, BB),    256, 0, stream>>>(vn, lcp, embA, lamG);
    k_epi2  <<<dim3(16, BB, 2), 256, 0, stream>>>(lamG, q_pre, stats, gamma, out);
  } else {
    k_fused <<<dim3(64, BB),    256, 0, stream>>>(vn, q_pre, stats, lcp, embA, gamma, out);
  }
}

// Round 10
// 214.577 us; speedup vs baseline: 1.0841x; 1.0660x over previous
//
#include <hip/hip_runtime.h>
#include <math.h>

#define BB 32
#define CC 256
#define NPIX 1024     // 32*32
#define KD 16
#define NHEADS 4
#define VDIM 64
#define RR 23
#define PADR 11
#define EPSBN 1e-5f

typedef short short8v __attribute__((ext_vector_type(8)));
typedef short short4v __attribute__((ext_vector_type(4)));
typedef float floatx4 __attribute__((ext_vector_type(4)));

__device__ __forceinline__ unsigned short f2bf(float f) {
  union { float f; unsigned u; } c; c.f = f;
  unsigned u = c.u;
  return (unsigned short)((u + 0x7FFFu + ((u >> 16) & 1u)) >> 16);
}
__device__ __forceinline__ float bf2f(unsigned short h) {
  union { unsigned u; float f; } c; c.u = ((unsigned)h) << 16;
  return c.f;
}

// raw stats layout: raw[0..63] q-sum, raw[64..127] q-sumsq,
//                   raw[128..191] v-sum, raw[192..255] v-sumsq
#define NINV (1.0f / 32768.0f)   // 1/(B*NPIX)

// ---------------- K0: emb->bf16 A-layout + W pack + zero raw sums -----------
__global__ __launch_bounds__(256) void k_prep(const float* __restrict__ emb,
    unsigned short* __restrict__ embA,
    const float* __restrict__ Wq, const float* __restrict__ Wk,
    const float* __restrict__ Wv, unsigned short* __restrict__ wA,
    float* __restrict__ raw) {
  int bid = blockIdx.x;
  if (bid == 0) raw[threadIdx.x] = 0.f;   // 256 threads cover 256 slots
  if (bid < 46) {
    int l = bid * 256 + threadIdx.x;
    if (l >= 23 * 16 * 32) return;
    int dr = l >> 9, rem = l & 511;
    int m = rem >> 5, kd = rem & 31;
    unsigned short val = 0;
    if (kd < 23) val = f2bf(emb[(size_t)m * 529 + dr * 23 + kd]);
    embA[l] = val;
  } else {
    int idx = (bid - 46) * 256 + threadIdx.x;  // 0..36863
    int j = idx & 7, lane = (idx >> 3) & 63, ks = (idx >> 9) & 7, ot = idx >> 12;
    int o = ot * 16 + (lane & 15);
    int c = ks * 32 + (lane >> 4) * 8 + j;
    const float* src = (o < 64) ? (Wq + (size_t)o * CC)
                     : (o < 80) ? (Wk + (size_t)(o - 64) * CC)
                                : (Wv + (size_t)(o - 80) * CC);
    wA[idx] = f2bf(src[c]);
  }
}

// ---------------- K1: 1x1-conv MFMA GEMM + BN partial-sum atomics -----------
__global__ __launch_bounds__(256) void k_proj(const float* __restrict__ x,
    const unsigned short* __restrict__ wA,
    float* __restrict__ q_pre, float* __restrict__ k_pre, float* __restrict__ v_pre,
    float* __restrict__ raw) {
  __shared__ float ssum[144], ssq[144];
  int b = blockIdx.y;
  int t = threadIdx.x;
  int s = t >> 6;                 // wave id = 16-pixel subtile
  int lane = t & 63;
  int nl = lane & 15, quad = lane >> 4;
  int pix = blockIdx.x * 64 + s * 16 + nl;

  if (t < 144) { ssum[t] = 0.f; ssq[t] = 0.f; }
  __syncthreads();

  const float* xb = x + ((size_t)b * CC) * NPIX + pix;
  const unsigned short* ap = wA + lane * 8;

  floatx4 acc[9];
#pragma unroll
  for (int i = 0; i < 9; ++i) acc[i] = (floatx4){0.f, 0.f, 0.f, 0.f};

#pragma unroll
  for (int ks = 0; ks < 8; ++ks) {
    union { short8v v; unsigned short u[8]; } bb;
    const float* xc = xb + ((size_t)(ks * 32 + quad * 8)) * NPIX;
#pragma unroll
    for (int j = 0; j < 8; ++j) bb.u[j] = f2bf(xc[(size_t)j * NPIX]);
#pragma unroll
    for (int ot = 0; ot < 9; ++ot) {
      short8v af = *(const short8v*)(ap + ((ot * 8 + ks) << 9));
      acc[ot] = __builtin_amdgcn_mfma_f32_16x16x32_bf16(af, bb.v, acc[ot], 0, 0, 0);
    }
  }

#pragma unroll
  for (int ot = 0; ot < 9; ++ot) {
#pragma unroll
    for (int r = 0; r < 4; ++r) {
      int o = ot * 16 + quad * 4 + r;
      float val = acc[ot][r];
      if (o < 64)      q_pre[((size_t)b * 64 + o) * NPIX + pix] = val;
      else if (o < 80) k_pre[((size_t)b * 16 + (o - 64)) * NPIX + pix] = val;
      else             v_pre[((size_t)b * 64 + (o - 80)) * NPIX + pix] = val;
    }
  }

  // ---- BN partial sums: reduce over 16-pixel lanes, LDS, 1 global atomic/ch
#pragma unroll
  for (int ot = 0; ot < 9; ++ot) {
#pragma unroll
    for (int r = 0; r < 4; ++r) {
      int o = ot * 16 + quad * 4 + r;
      if (o >= 64 && o < 80) continue;    // k-channels have no BN
      float v1 = acc[ot][r];
      float v2 = v1 * v1;
#pragma unroll
      for (int m = 1; m < 16; m <<= 1) {
        v1 += __shfl_xor(v1, m);
        v2 += __shfl_xor(v2, m);
      }
      if (nl == 0) {
        atomicAdd(&ssum[o], v1);
        atomicAdd(&ssq[o], v2);
      }
    }
  }
  __syncthreads();
  if (t < 64) {                       // q channels
    atomicAdd(&raw[t], ssum[t]);
    atomicAdd(&raw[64 + t], ssq[t]);
  } else if (t < 128) {               // v channels (o = t+16)
    atomicAdd(&raw[64 + t], ssum[t + 16]);     // raw[128..191]
    atomicAdd(&raw[192 + (t - 64)], ssq[t + 16]);
  }
}

// ---------------- K2: v-normalize (inline stat finalize) + softmax ----------
__global__ __launch_bounds__(256) void k_nvsm(float* __restrict__ vn,
    const float* __restrict__ raw,
    const float* __restrict__ bn_v_w, const float* __restrict__ bn_v_b,
    const float* __restrict__ k_pre, float* __restrict__ p) {
  __shared__ float vsc[64], vsh[64];
  __shared__ float shm[4], shs[4];
  int b = blockIdx.y, bx = blockIdx.x, t = threadIdx.x;
  if (bx < 16) {
    // ---- norm_v chunk bx ----
    if (t < 64) {
      float mean = raw[128 + t] * NINV;
      float var = raw[192 + t] * NINV - mean * mean;
      float sc = rsqrtf(var + EPSBN) * bn_v_w[t];
      vsc[t] = sc;
      vsh[t] = bn_v_b[t] - mean * sc;
    }
    __syncthreads();
    int n0 = bx * 64;
    for (int l = t; l < 4096; l += 256) {
      int o = l >> 6, nn = l & 63;
      size_t a = ((size_t)b * 64 + o) * NPIX + n0 + nn;
      vn[a] = fmaf(vn[a], vsc[o], vsh[o]);
    }
  } else {
    // ---- softmax k = bx-16 ----
    int k = bx - 16;
    const float* src = k_pre + ((size_t)b * 16 + k) * NPIX;
    float v[4];
    float mx = -1e30f;
#pragma unroll
    for (int i = 0; i < 4; ++i) { v[i] = src[t + 256 * i]; mx = fmaxf(mx, v[i]); }
#pragma unroll
    for (int off = 32; off > 0; off >>= 1) mx = fmaxf(mx, __shfl_down(mx, off));
    if ((t & 63) == 0) shm[t >> 6] = mx;
    __syncthreads();
    mx = fmaxf(fmaxf(shm[0], shm[1]), fmaxf(shm[2], shm[3]));
    float s = 0.f;
#pragma unroll
    for (int i = 0; i < 4; ++i) { v[i] = __expf(v[i] - mx); s += v[i]; }
#pragma unroll
    for (int off = 32; off > 0; off >>= 1) s += __shfl_down(s, off);
    if ((t & 63) == 0) shs[t >> 6] = s;
    __syncthreads();
    float r = 1.0f / (shs[0] + shs[1] + shs[2] + shs[3]);
    float* dst = p + ((size_t)b * 16 + k) * NPIX;
#pragma unroll
    for (int i = 0; i < 4; ++i) dst[t + 256 * i] = v[i] * r;
  }
}

// ---------------- shared LDS layout for conv kernel ----------------
#define IMG_RS 68            // shorts per padded row
#define IMG_CS 3728          // shorts per copy (54*68=3672 used + 56 pad)
#define LAM_RS 1032          // lambda row stride in shorts (1024 + 8 pad)

union KMainLDS {
  short imgc[4 * IMG_CS];   // 29824 B
  short lam[16 * LAM_RS];   // 33024 B
};

__device__ __forceinline__ short8v ld_win(const short* p) {
  union { short8v s8; short4v s4[2]; } bu;
  bu.s4[0] = *(const short4v*)p;
  bu.s4[1] = *(const short4v*)(p + 4);
  return bu.s8;
}

// ---------------- K5a: MFMA conv + inline lambda_c -> lamG ------------------
__global__ __launch_bounds__(256, 3) void k_conv(const float* __restrict__ vn,
    const float* __restrict__ p, const unsigned short* __restrict__ embA,
    unsigned short* __restrict__ lamG) {
  __shared__ __align__(16) KMainLDS u;
  __shared__ float lcv[16];
  __shared__ float red[256];
  int b = blockIdx.y, v = blockIdx.x, t = threadIdx.x;

  int4* z4 = (int4*)u.imgc;
  for (int l = t; l < 1864; l += 256) z4[l] = make_int4(0, 0, 0, 0);

  // inline lambda_c partials: lcv[k] = sum_n p[b,k,n]*vn[b,v,n]
  {
    int kk = t & 15, ch = t >> 4;
    const float* pp = p + ((size_t)b * 16 + kk) * NPIX + ch * 64;
    const float* vv = vn + ((size_t)b * 64 + v) * NPIX + ch * 64;
    float part = 0.f;
#pragma unroll 8
    for (int i = 0; i < 64; ++i) part = fmaf(pp[i], vv[i], part);
    red[t] = part;
  }
  __syncthreads();
  if (t < 16) {
    float s = 0.f;
#pragma unroll
    for (int c = 0; c < 16; ++c) s += red[c * 16 + t];
    lcv[t] = s;
  }

  const float* vsrc = vn + ((size_t)b * 64 + v) * NPIX;
  for (int l = t; l < 512; l += 256) {
    int pix = l * 2;
    int y = pix >> 5, xx = pix & 31;
    float2 vv = *(const float2*)(vsrc + pix);
    unsigned short h0 = f2bf(vv.x), h1 = f2bf(vv.y);
#pragma unroll
    for (int s = 0; s < 4; ++s) {
      int base = s * IMG_CS + (y + PADR) * IMG_RS + xx + PADR + s;
      u.imgc[base] = (short)h0;
      u.imgc[base + 1] = (short)h1;
    }
  }
  __syncthreads();

  int lane = t & 63, wv = t >> 6;
  int nl = lane & 15, quad = lane >> 4;
  int y0 = wv * 8;
  int scopy = (4 - (nl & 3)) & 3;
  int colbase = scopy * IMG_CS + nl + quad * 8 + scopy;
  const unsigned short* aptr = embA + nl * 32 + quad * 8;

  floatx4 acc[16];
#pragma unroll
  for (int i = 0; i < 16; ++i) acc[i] = (floatx4){0.f, 0.f, 0.f, 0.f};

  // prologue: cache rows y0..y0+7 (slot = row & 7)
  short8v bfrag[8][2];
#pragma unroll
  for (int rr = 0; rr < 8; ++rr) {
    const short* rp = &u.imgc[(y0 + rr) * IMG_RS + colbase];
    bfrag[rr][0] = ld_win(rp);
    bfrag[rr][1] = ld_win(rp + 16);
  }

  // depth-2 embA prefetch ring
  short8v a0 = *(const short8v*)aptr;
  short8v a1 = *(const short8v*)(aptr + 512);
#pragma unroll
  for (int dr = 0; dr < RR; ++dr) {
    short8v afrag = a0;
    a0 = a1;
    if (dr < RR - 2) a1 = *(const short8v*)(aptr + (dr + 2) * 512);
#pragma unroll
    for (int rr = 0; rr < 8; ++rr) {
      int slot = (dr + rr) & 7;
      acc[rr * 2 + 0] = __builtin_amdgcn_mfma_f32_16x16x32_bf16(afrag, bfrag[slot][0], acc[rr * 2 + 0], 0, 0, 0);
      acc[rr * 2 + 1] = __builtin_amdgcn_mfma_f32_16x16x32_bf16(afrag, bfrag[slot][1], acc[rr * 2 + 1], 0, 0, 0);
    }
    if (dr < RR - 1) {
      const short* rp = &u.imgc[(y0 + dr + 8) * IMG_RS + colbase];
      int slot = dr & 7;
      bfrag[slot][0] = ld_win(rp);
      bfrag[slot][1] = ld_win(rp + 16);
    }
  }

  __syncthreads();
#pragma unroll
  for (int tt = 0; tt < 16; ++tt) {
    int y = y0 + (tt >> 1), c0 = (tt & 1) << 4;
    int pix = y * 32 + c0 + nl;
#pragma unroll
    for (int r = 0; r < 4; ++r)
      u.lam[(quad * 4 + r) * LAM_RS + pix] = (short)f2bf(acc[tt][r] + lcv[quad * 4 + r]);
  }
  __syncthreads();

  // coalesced LDS -> global copy of lambda (16 rows x 1024 bf16 = 2048 uint4)
  uint4* dst = (uint4*)(lamG + ((size_t)(b * 64 + v)) * 16 * 1024);
  for (int idx = t; idx < 2048; idx += 256) {
    int row = idx >> 7, col = idx & 127;
    dst[row * 128 + col] = *(const uint4*)&u.lam[row * LAM_RS + col * 8];
  }
}

// ---------------- K5b: chunk-grid epilogue, z-split, inline q-stats ---------
__global__ __launch_bounds__(256) void k_epi2(const unsigned short* __restrict__ lamG,
    const float* __restrict__ q_pre, const float* __restrict__ raw,
    const float* __restrict__ bn_q_w, const float* __restrict__ bn_q_b,
    const float* __restrict__ gamma, float* __restrict__ out) {
  __shared__ float qs[64 * 64];   // [o][n] 16 KB
  __shared__ float qsc[64], qsh[64];
  int b = blockIdx.y, nc = blockIdx.x, z = blockIdx.z, t = threadIdx.x;
  if (t < 64) {
    float mean = raw[t] * NINV;
    float var = raw[64 + t] * NINV - mean * mean;
    float sc = rsqrtf(var + EPSBN) * bn_q_w[t];
    qsc[t] = sc;
    qsh[t] = bn_q_b[t] - mean * sc;
  }
  __syncthreads();
  int n0 = nc * 64;
  for (int l = t; l < 4096; l += 256) {
    int o = l >> 6, nn = l & 63;
    qs[l] = fmaf(q_pre[((size_t)b * 64 + o) * NPIX + n0 + nn], qsc[o], qsh[o]);
  }
  __syncthreads();
  float g1 = 1.0f + gamma[0];
  int p0 = (t & 15) * 4;
  int g = t >> 4;                 // 0..15
#pragma unroll
  for (int vi = 0; vi < 2; ++vi) {
    int v = z * 32 + vi * 16 + g;
    const unsigned short* ls = lamG + ((size_t)(b * 64 + v)) * 16 * 1024 + n0 + p0;
    float yacc[4][4];
#pragma unroll
    for (int h = 0; h < 4; ++h)
#pragma unroll
      for (int i = 0; i < 4; ++i) yacc[h][i] = 0.f;
#pragma unroll
    for (int k = 0; k < 16; ++k) {
      uint2 w = *(const uint2*)(ls + k * 1024);
      float l0 = bf2f((unsigned short)(w.x & 0xffffu));
      float l1 = bf2f((unsigned short)(w.x >> 16));
      float l2 = bf2f((unsigned short)(w.y & 0xffffu));
      float l3 = bf2f((unsigned short)(w.y >> 16));
#pragma unroll
      for (int h = 0; h < 4; ++h) {
        const float* qrow = &qs[(h * 16 + k) * 64 + p0];
        yacc[h][0] = fmaf(qrow[0], l0, yacc[h][0]);
        yacc[h][1] = fmaf(qrow[1], l1, yacc[h][1]);
        yacc[h][2] = fmaf(qrow[2], l2, yacc[h][2]);
        yacc[h][3] = fmaf(qrow[3], l3, yacc[h][3]);
      }
    }
#pragma unroll
    for (int h = 0; h < 4; ++h) {
      float4 r;
      r.x = g1 * yacc[h][0]; r.y = g1 * yacc[h][1];
      r.z = g1 * yacc[h][2]; r.w = g1 * yacc[h][3];
      *(float4*)&out[((size_t)b * 256 + h * 64 + v) * NPIX + n0 + p0] = r;
    }
  }
}

// ---------------- K5 fallback: fused conv+epilogue (updated for raw stats) --
__global__ __launch_bounds__(256, 3) void k_fused(const float* __restrict__ vn,
    const float* __restrict__ q_pre, const float* __restrict__ raw,
    const float* __restrict__ bn_q_w, const float* __restrict__ bn_q_b,
    const float* __restrict__ p, const unsigned short* __restrict__ embA,
    const float* __restrict__ gamma, float* __restrict__ out) {
  __shared__ __align__(16) KMainLDS u;
  __shared__ float lcv[16];
  __shared__ float red[256];
  __shared__ float qsc[64], qsh[64];
  int b = blockIdx.y, v = blockIdx.x, t = threadIdx.x;

  int4* z4 = (int4*)u.imgc;
  for (int l = t; l < 1864; l += 256) z4[l] = make_int4(0, 0, 0, 0);
  if (t < 64) {
    float mean = raw[t] * NINV;
    float var = raw[64 + t] * NINV - mean * mean;
    float sc = rsqrtf(var + EPSBN) * bn_q_w[t];
    qsc[t] = sc;
    qsh[t] = bn_q_b[t] - mean * sc;
  }
  {
    int kk = t & 15, ch = t >> 4;
    const float* pp = p + ((size_t)b * 16 + kk) * NPIX + ch * 64;
    const float* vv = vn + ((size_t)b * 64 + v) * NPIX + ch * 64;
    float part = 0.f;
#pragma unroll 8
    for (int i = 0; i < 64; ++i) part = fmaf(pp[i], vv[i], part);
    red[t] = part;
  }
  __syncthreads();
  if (t < 16) {
    float s = 0.f;
#pragma unroll
    for (int c = 0; c < 16; ++c) s += red[c * 16 + t];
    lcv[t] = s;
  }

  const float* vsrc = vn + ((size_t)b * 64 + v) * NPIX;
  for (int l = t; l < 512; l += 256) {
    int pix = l * 2;
    int y = pix >> 5, xx = pix & 31;
    float2 vv = *(const float2*)(vsrc + pix);
    unsigned short h0 = f2bf(vv.x), h1 = f2bf(vv.y);
#pragma unroll
    for (int s = 0; s < 4; ++s) {
      int base = s * IMG_CS + (y + PADR) * IMG_RS + xx + PADR + s;
      u.imgc[base] = (short)h0;
      u.imgc[base + 1] = (short)h1;
    }
  }
  __syncthreads();

  int lane = t & 63, wv = t >> 6;
  int nl = lane & 15, quad = lane >> 4;
  int y0 = wv * 8;
  int scopy = (4 - (nl & 3)) & 3;
  int colbase = scopy * IMG_CS + nl + quad * 8 + scopy;
  const unsigned short* aptr = embA + nl * 32 + quad * 8;

  floatx4 acc[16];
#pragma unroll
  for (int i = 0; i < 16; ++i) acc[i] = (floatx4){0.f, 0.f, 0.f, 0.f};

  short8v bfrag[8][2];
#pragma unroll
  for (int rr = 0; rr < 8; ++rr) {
    const short* rp = &u.imgc[(y0 + rr) * IMG_RS + colbase];
    bfrag[rr][0] = ld_win(rp);
    bfrag[rr][1] = ld_win(rp + 16);
  }

  short8v a0 = *(const short8v*)aptr;
  short8v a1 = *(const short8v*)(aptr + 512);
#pragma unroll
  for (int dr = 0; dr < RR; ++dr) {
    short8v afrag = a0;
    a0 = a1;
    if (dr < RR - 2) a1 = *(const short8v*)(aptr + (dr + 2) * 512);
#pragma unroll
    for (int rr = 0; rr < 8; ++rr) {
      int slot = (dr + rr) & 7;
      acc[rr * 2 + 0] = __builtin_amdgcn_mfma_f32_16x16x32_bf16(afrag, bfrag[slot][0], acc[rr * 2 + 0], 0, 0, 0);
      acc[rr * 2 + 1] = __builtin_amdgcn_mfma_f32_16x16x32_bf16(afrag, bfrag[slot][1], acc[rr * 2 + 1], 0, 0, 0);
    }
    if (dr < RR - 1) {
      const short* rp = &u.imgc[(y0 + dr + 8) * IMG_RS + colbase];
      int slot = dr & 7;
      bfrag[slot][0] = ld_win(rp);
      bfrag[slot][1] = ld_win(rp + 16);
    }
  }

  __syncthreads();
#pragma unroll
  for (int tt = 0; tt < 16; ++tt) {
    int y = y0 + (tt >> 1), c0 = (tt & 1) << 4;
    int pix = y * 32 + c0 + nl;
#pragma unroll
    for (int r = 0; r < 4; ++r)
      u.lam[(quad * 4 + r) * LAM_RS + pix] = (short)f2bf(acc[tt][r] + lcv[quad * 4 + r]);
  }
  __syncthreads();

  int p0 = t * 4;
  float yacc[4][4];
#pragma unroll
  for (int h = 0; h < 4; ++h)
#pragma unroll
    for (int i = 0; i < 4; ++i) yacc[h][i] = 0.f;
  const float* qb = q_pre + ((size_t)b * 64) * NPIX + p0;
#pragma unroll
  for (int k = 0; k < 16; ++k) {
    uint2 w = *(const uint2*)&u.lam[k * LAM_RS + p0];
    float l0 = bf2f((unsigned short)(w.x & 0xffffu));
    float l1 = bf2f((unsigned short)(w.x >> 16));
    float l2 = bf2f((unsigned short)(w.y & 0xffffu));
    float l3 = bf2f((unsigned short)(w.y >> 16));
#pragma unroll
    for (int h = 0; h < 4; ++h) {
      int o = h * 16 + k;
      float4 qv = *(const float4*)(qb + (size_t)o * NPIX);
      yacc[h][0] = fmaf(fmaf(qv.x, qsc[o], qsh[o]), l0, yacc[h][0]);
      yacc[h][1] = fmaf(fmaf(qv.y, qsc[o], qsh[o]), l1, yacc[h][1]);
      yacc[h][2] = fmaf(fmaf(qv.z, qsc[o], qsh[o]), l2, yacc[h][2]);
      yacc[h][3] = fmaf(fmaf(qv.w, qsc[o], qsh[o]), l3, yacc[h][3]);
    }
  }
  float g1 = 1.0f + gamma[0];
#pragma unroll
  for (int h = 0; h < 4; ++h) {
    float4 r;
    r.x = g1 * yacc[h][0]; r.y = g1 * yacc[h][1];
    r.z = g1 * yacc[h][2]; r.w = g1 * yacc[h][3];
    *(float4*)&out[((size_t)b * 256 + h * 64 + v) * NPIX + p0] = r;
  }
}

extern "C" void kernel_launch(void* const* d_in, const int* in_sizes, int n_in,
                              void* d_out, int out_size, void* d_ws, size_t ws_size,
                              hipStream_t stream) {
  const float* x      = (const float*)d_in[0];
  const float* Wq     = (const float*)d_in[1];
  const float* bn_q_w = (const float*)d_in[2];
  const float* bn_q_b = (const float*)d_in[3];
  const float* Wk     = (const float*)d_in[4];
  const float* Wv     = (const float*)d_in[5];
  const float* bn_v_w = (const float*)d_in[6];
  const float* bn_v_b = (const float*)d_in[7];
  const float* emb    = (const float*)d_in[8];
  const float* gamma  = (const float*)d_in[9];
  float* out = (float*)d_out;

  float* ws    = (float*)d_ws;
  float* q_pre = ws;                                     // B*64*N
  float* k_pre = q_pre + (size_t)BB * 64 * NPIX;         // B*16*N
  float* vn    = k_pre + (size_t)BB * 16 * NPIX;         // B*64*N
  float* p     = vn    + (size_t)BB * 64 * NPIX;         // B*16*N
  float* raw   = p     + (size_t)BB * 16 * NPIX;         // 256 raw BN sums
  unsigned short* embA = (unsigned short*)(raw + 256);   // 23*16*32 ushorts
  unsigned short* wA   = embA + 23 * 16 * 32;            // 144*256 ushorts
  unsigned short* lamG = wA + 144 * 256;                 // B*64*16*N ushorts (64 MB)

  size_t need = ((size_t)(lamG - (unsigned short*)ws)) * 2
              + (size_t)BB * 64 * 16 * NPIX * 2;

  k_prep  <<<dim3(190),       256, 0, stream>>>(emb, embA, Wq, Wk, Wv, wA, raw);
  k_proj  <<<dim3(16, BB),    256, 0, stream>>>(x, wA, q_pre, k_pre, vn, raw);
  k_nvsm  <<<dim3(32, BB),    256, 0, stream>>>(vn, raw, bn_v_w, bn_v_b, k_pre, p);
  if (ws_size >= need) {
    k_conv<<<dim3(64, BB),    256, 0, stream>>>(vn, p, embA, lamG);
    k_epi2<<<dim3(16, BB, 2), 256, 0, stream>>>(lamG, q_pre, raw, bn_q_w, bn_q_b, gamma, out);
  } else {
    k_fused<<<dim3(64, BB),   256, 0, stream>>>(vn, q_pre, raw, bn_q_w, bn_q_b, p, embA, gamma, out);
  }
}

// Round 11
// 208.848 us; speedup vs baseline: 1.1139x; 1.0274x over previous
//
#include <hip/hip_runtime.h>
#include <math.h>

#define BB 32
#define CC 256
#define NPIX 1024     // 32*32
#define KD 16
#define NHEADS 4
#define VDIM 64
#define RR 23
#define PADR 11
#define EPSBN 1e-5f

typedef short short8v __attribute__((ext_vector_type(8)));
typedef short short4v __attribute__((ext_vector_type(4)));
typedef float floatx4 __attribute__((ext_vector_type(4)));

__device__ __forceinline__ unsigned short f2bf(float f) {
  union { float f; unsigned u; } c; c.f = f;
  unsigned u = c.u;
  return (unsigned short)((u + 0x7FFFu + ((u >> 16) & 1u)) >> 16);
}
__device__ __forceinline__ float bf2f(unsigned short h) {
  union { unsigned u; float f; } c; c.u = ((unsigned)h) << 16;
  return c.f;
}

// raw stats layout: raw[0..63] q-sum, raw[64..127] q-sumsq,
//                   raw[128..191] v-sum, raw[192..255] v-sumsq
#define NINV (1.0f / 32768.0f)   // 1/(B*NPIX)

// ---------------- K0: emb->bf16 A-layout + W pack + zero raw sums -----------
__global__ __launch_bounds__(256) void k_prep(const float* __restrict__ emb,
    unsigned short* __restrict__ embA,
    const float* __restrict__ Wq, const float* __restrict__ Wk,
    const float* __restrict__ Wv, unsigned short* __restrict__ wA,
    float* __restrict__ raw) {
  int bid = blockIdx.x;
  if (bid == 0) raw[threadIdx.x] = 0.f;   // 256 threads cover 256 slots
  if (bid < 46) {
    int l = bid * 256 + threadIdx.x;
    if (l >= 23 * 16 * 32) return;
    int dr = l >> 9, rem = l & 511;
    int m = rem >> 5, kd = rem & 31;
    unsigned short val = 0;
    if (kd < 23) val = f2bf(emb[(size_t)m * 529 + dr * 23 + kd]);
    embA[l] = val;
  } else {
    int idx = (bid - 46) * 256 + threadIdx.x;  // 0..36863
    int j = idx & 7, lane = (idx >> 3) & 63, ks = (idx >> 9) & 7, ot = idx >> 12;
    int o = ot * 16 + (lane & 15);
    int c = ks * 32 + (lane >> 4) * 8 + j;
    const float* src = (o < 64) ? (Wq + (size_t)o * CC)
                     : (o < 80) ? (Wk + (size_t)(o - 64) * CC)
                                : (Wv + (size_t)(o - 80) * CC);
    wA[idx] = f2bf(src[c]);
  }
}

// ---------------- K1: 1x1-conv MFMA GEMM + BN partial-sum atomics -----------
__global__ __launch_bounds__(256) void k_proj(const float* __restrict__ x,
    const unsigned short* __restrict__ wA,
    float* __restrict__ q_pre, float* __restrict__ k_pre, float* __restrict__ v_pre,
    float* __restrict__ raw) {
  __shared__ float ssum[144], ssq[144];
  int b = blockIdx.y;
  int t = threadIdx.x;
  int s = t >> 6;                 // wave id = 16-pixel subtile
  int lane = t & 63;
  int nl = lane & 15, quad = lane >> 4;
  int pix = blockIdx.x * 64 + s * 16 + nl;

  if (t < 144) { ssum[t] = 0.f; ssq[t] = 0.f; }
  __syncthreads();

  const float* xb = x + ((size_t)b * CC) * NPIX + pix;
  const unsigned short* ap = wA + lane * 8;

  floatx4 acc[9];
#pragma unroll
  for (int i = 0; i < 9; ++i) acc[i] = (floatx4){0.f, 0.f, 0.f, 0.f};

#pragma unroll
  for (int ks = 0; ks < 8; ++ks) {
    union { short8v v; unsigned short u[8]; } bb;
    const float* xc = xb + ((size_t)(ks * 32 + quad * 8)) * NPIX;
#pragma unroll
    for (int j = 0; j < 8; ++j) bb.u[j] = f2bf(xc[(size_t)j * NPIX]);
#pragma unroll
    for (int ot = 0; ot < 9; ++ot) {
      short8v af = *(const short8v*)(ap + ((ot * 8 + ks) << 9));
      acc[ot] = __builtin_amdgcn_mfma_f32_16x16x32_bf16(af, bb.v, acc[ot], 0, 0, 0);
    }
  }

#pragma unroll
  for (int ot = 0; ot < 9; ++ot) {
#pragma unroll
    for (int r = 0; r < 4; ++r) {
      int o = ot * 16 + quad * 4 + r;
      float val = acc[ot][r];
      if (o < 64)      q_pre[((size_t)b * 64 + o) * NPIX + pix] = val;
      else if (o < 80) k_pre[((size_t)b * 16 + (o - 64)) * NPIX + pix] = val;
      else             v_pre[((size_t)b * 64 + (o - 80)) * NPIX + pix] = val;
    }
  }

  // ---- BN partial sums: reduce over 16-pixel lanes, LDS, 1 global atomic/ch
#pragma unroll
  for (int ot = 0; ot < 9; ++ot) {
#pragma unroll
    for (int r = 0; r < 4; ++r) {
      int o = ot * 16 + quad * 4 + r;
      if (o >= 64 && o < 80) continue;    // k-channels have no BN
      float v1 = acc[ot][r];
      float v2 = v1 * v1;
#pragma unroll
      for (int m = 1; m < 16; m <<= 1) {
        v1 += __shfl_xor(v1, m);
        v2 += __shfl_xor(v2, m);
      }
      if (nl == 0) {
        atomicAdd(&ssum[o], v1);
        atomicAdd(&ssq[o], v2);
      }
    }
  }
  __syncthreads();
  if (t < 64) {                       // q channels
    atomicAdd(&raw[t], ssum[t]);
    atomicAdd(&raw[64 + t], ssq[t]);
  } else if (t < 128) {               // v channels (o = t+16)
    atomicAdd(&raw[64 + t], ssum[t + 16]);     // raw[128..191]
    atomicAdd(&raw[192 + (t - 64)], ssq[t + 16]);
  }
}

// ---------------- K2: v-normalize (inline stat finalize) + softmax ----------
__global__ __launch_bounds__(256) void k_nvsm(float* __restrict__ vn,
    const float* __restrict__ raw,
    const float* __restrict__ bn_v_w, const float* __restrict__ bn_v_b,
    const float* __restrict__ k_pre, float* __restrict__ p) {
  __shared__ float vsc[64], vsh[64];
  __shared__ float shm[4], shs[4];
  int b = blockIdx.y, bx = blockIdx.x, t = threadIdx.x;
  if (bx < 16) {
    // ---- norm_v chunk bx ----
    if (t < 64) {
      float mean = raw[128 + t] * NINV;
      float var = raw[192 + t] * NINV - mean * mean;
      float sc = rsqrtf(var + EPSBN) * bn_v_w[t];
      vsc[t] = sc;
      vsh[t] = bn_v_b[t] - mean * sc;
    }
    __syncthreads();
    int n0 = bx * 64;
    for (int l = t; l < 4096; l += 256) {
      int o = l >> 6, nn = l & 63;
      size_t a = ((size_t)b * 64 + o) * NPIX + n0 + nn;
      vn[a] = fmaf(vn[a], vsc[o], vsh[o]);
    }
  } else {
    // ---- softmax k = bx-16 ----
    int k = bx - 16;
    const float* src = k_pre + ((size_t)b * 16 + k) * NPIX;
    float v[4];
    float mx = -1e30f;
#pragma unroll
    for (int i = 0; i < 4; ++i) { v[i] = src[t + 256 * i]; mx = fmaxf(mx, v[i]); }
#pragma unroll
    for (int off = 32; off > 0; off >>= 1) mx = fmaxf(mx, __shfl_down(mx, off));
    if ((t & 63) == 0) shm[t >> 6] = mx;
    __syncthreads();
    mx = fmaxf(fmaxf(shm[0], shm[1]), fmaxf(shm[2], shm[3]));
    float s = 0.f;
#pragma unroll
    for (int i = 0; i < 4; ++i) { v[i] = __expf(v[i] - mx); s += v[i]; }
#pragma unroll
    for (int off = 32; off > 0; off >>= 1) s += __shfl_down(s, off);
    if ((t & 63) == 0) shs[t >> 6] = s;
    __syncthreads();
    float r = 1.0f / (shs[0] + shs[1] + shs[2] + shs[3]);
    float* dst = p + ((size_t)b * 16 + k) * NPIX;
#pragma unroll
    for (int i = 0; i < 4; ++i) dst[t + 256 * i] = v[i] * r;
  }
}

// ---------------- shared LDS layout for conv kernel ----------------
#define IMG_RS 68            // shorts per padded row
#define IMG_CS 3728          // shorts per copy (54*68=3672 used + 56 pad)
#define LAM_RS 1032          // lambda row stride in shorts (1024 + 8 pad)

union KMainLDS {
  short imgc[4 * IMG_CS];   // 29824 B
  short lam[16 * LAM_RS];   // 33024 B
};

__device__ __forceinline__ short8v ld_win(const short* p) {
  union { short8v s8; short4v s4[2]; } bu;
  bu.s4[0] = *(const short4v*)p;
  bu.s4[1] = *(const short4v*)(p + 4);
  return bu.s8;
}

// ---------------- K5a: MFMA conv + coalesced inline lambda_c -> lamG --------
// lambda_c folded into the staging pass: each staged float2 of vn also dots
// against the 16 p-rows at the SAME pixel (adjacent lanes -> adjacent 8B,
// fully coalesced), accumulating part[16] in registers; 64-lane shfl reduce +
// 4-wave LDS combine. Replaces R9's 128 uncoalesced scalar loads/thread.
__global__ __launch_bounds__(256, 3) void k_conv(const float* __restrict__ vn,
    const float* __restrict__ p, const unsigned short* __restrict__ embA,
    unsigned short* __restrict__ lamG) {
  __shared__ __align__(16) KMainLDS u;
  __shared__ float lcv[16];
  __shared__ float red[64];
  int b = blockIdx.y, v = blockIdx.x, t = threadIdx.x;
  int lane = t & 63, wv = t >> 6;

  int4* z4 = (int4*)u.imgc;
  for (int l = t; l < 1864; l += 256) z4[l] = make_int4(0, 0, 0, 0);
  __syncthreads();

  const float* vsrc = vn + ((size_t)b * 64 + v) * NPIX;
  const float* psrc = p + (size_t)b * 16 * NPIX;
  float part[16];
#pragma unroll
  for (int k = 0; k < 16; ++k) part[k] = 0.f;

  for (int l = t; l < 512; l += 256) {
    int pix = l * 2;
    int y = pix >> 5, xx = pix & 31;
    float2 vv = *(const float2*)(vsrc + pix);
    unsigned short h0 = f2bf(vv.x), h1 = f2bf(vv.y);
#pragma unroll
    for (int s = 0; s < 4; ++s) {
      int base = s * IMG_CS + (y + PADR) * IMG_RS + xx + PADR + s;
      u.imgc[base] = (short)h0;
      u.imgc[base + 1] = (short)h1;
    }
#pragma unroll
    for (int k = 0; k < 16; ++k) {
      float2 pk = *(const float2*)(psrc + (size_t)k * NPIX + pix);
      part[k] = fmaf(pk.x, vv.x, fmaf(pk.y, vv.y, part[k]));
    }
  }
  // 64-lane butterfly reduce each part[k]
#pragma unroll
  for (int k = 0; k < 16; ++k) {
#pragma unroll
    for (int m = 1; m < 64; m <<= 1) part[k] += __shfl_xor(part[k], m);
  }
  if (lane == 0) {
#pragma unroll
    for (int k = 0; k < 16; ++k) red[wv * 16 + k] = part[k];
  }
  __syncthreads();
  if (t < 16)
    lcv[t] = red[t] + red[16 + t] + red[32 + t] + red[48 + t];

  int nl = lane & 15, quad = lane >> 4;
  int y0 = wv * 8;
  int scopy = (4 - (nl & 3)) & 3;
  int colbase = scopy * IMG_CS + nl + quad * 8 + scopy;
  const unsigned short* aptr = embA + nl * 32 + quad * 8;

  floatx4 acc[16];
#pragma unroll
  for (int i = 0; i < 16; ++i) acc[i] = (floatx4){0.f, 0.f, 0.f, 0.f};

  // prologue: cache rows y0..y0+7 (slot = row & 7)
  short8v bfrag[8][2];
#pragma unroll
  for (int rr = 0; rr < 8; ++rr) {
    const short* rp = &u.imgc[(y0 + rr) * IMG_RS + colbase];
    bfrag[rr][0] = ld_win(rp);
    bfrag[rr][1] = ld_win(rp + 16);
  }

  // depth-2 embA prefetch ring
  short8v a0 = *(const short8v*)aptr;
  short8v a1 = *(const short8v*)(aptr + 512);
#pragma unroll
  for (int dr = 0; dr < RR; ++dr) {
    short8v afrag = a0;
    a0 = a1;
    if (dr < RR - 2) a1 = *(const short8v*)(aptr + (dr + 2) * 512);
#pragma unroll
    for (int rr = 0; rr < 8; ++rr) {
      int slot = (dr + rr) & 7;
      acc[rr * 2 + 0] = __builtin_amdgcn_mfma_f32_16x16x32_bf16(afrag, bfrag[slot][0], acc[rr * 2 + 0], 0, 0, 0);
      acc[rr * 2 + 1] = __builtin_amdgcn_mfma_f32_16x16x32_bf16(afrag, bfrag[slot][1], acc[rr * 2 + 1], 0, 0, 0);
    }
    if (dr < RR - 1) {
      const short* rp = &u.imgc[(y0 + dr + 8) * IMG_RS + colbase];
      int slot = dr & 7;
      bfrag[slot][0] = ld_win(rp);
      bfrag[slot][1] = ld_win(rp + 16);
    }
  }

  __syncthreads();
#pragma unroll
  for (int tt = 0; tt < 16; ++tt) {
    int y = y0 + (tt >> 1), c0 = (tt & 1) << 4;
    int pix = y * 32 + c0 + nl;
#pragma unroll
    for (int r = 0; r < 4; ++r)
      u.lam[(quad * 4 + r) * LAM_RS + pix] = (short)f2bf(acc[tt][r] + lcv[quad * 4 + r]);
  }
  __syncthreads();

  // coalesced LDS -> global copy of lambda (16 rows x 1024 bf16 = 2048 uint4)
  uint4* dst = (uint4*)(lamG + ((size_t)(b * 64 + v)) * 16 * 1024);
  for (int idx = t; idx < 2048; idx += 256) {
    int row = idx >> 7, col = idx & 127;
    dst[row * 128 + col] = *(const uint4*)&u.lam[row * LAM_RS + col * 8];
  }
}

// ---------------- K5b: chunk-grid epilogue, z-split, inline q-stats ---------
__global__ __launch_bounds__(256) void k_epi2(const unsigned short* __restrict__ lamG,
    const float* __restrict__ q_pre, const float* __restrict__ raw,
    const float* __restrict__ bn_q_w, const float* __restrict__ bn_q_b,
    const float* __restrict__ gamma, float* __restrict__ out) {
  __shared__ float qs[64 * 64];   // [o][n] 16 KB
  __shared__ float qsc[64], qsh[64];
  int b = blockIdx.y, nc = blockIdx.x, z = blockIdx.z, t = threadIdx.x;
  if (t < 64) {
    float mean = raw[t] * NINV;
    float var = raw[64 + t] * NINV - mean * mean;
    float sc = rsqrtf(var + EPSBN) * bn_q_w[t];
    qsc[t] = sc;
    qsh[t] = bn_q_b[t] - mean * sc;
  }
  __syncthreads();
  int n0 = nc * 64;
  for (int l = t; l < 4096; l += 256) {
    int o = l >> 6, nn = l & 63;
    qs[l] = fmaf(q_pre[((size_t)b * 64 + o) * NPIX + n0 + nn], qsc[o], qsh[o]);
  }
  __syncthreads();
  float g1 = 1.0f + gamma[0];
  int p0 = (t & 15) * 4;
  int g = t >> 4;                 // 0..15
#pragma unroll
  for (int vi = 0; vi < 2; ++vi) {
    int v = z * 32 + vi * 16 + g;
    const unsigned short* ls = lamG + ((size_t)(b * 64 + v)) * 16 * 1024 + n0 + p0;
    float yacc[4][4];
#pragma unroll
    for (int h = 0; h < 4; ++h)
#pragma unroll
      for (int i = 0; i < 4; ++i) yacc[h][i] = 0.f;
#pragma unroll
    for (int k = 0; k < 16; ++k) {
      uint2 w = *(const uint2*)(ls + k * 1024);
      float l0 = bf2f((unsigned short)(w.x & 0xffffu));
      float l1 = bf2f((unsigned short)(w.x >> 16));
      float l2 = bf2f((unsigned short)(w.y & 0xffffu));
      float l3 = bf2f((unsigned short)(w.y >> 16));
#pragma unroll
      for (int h = 0; h < 4; ++h) {
        const float* qrow = &qs[(h * 16 + k) * 64 + p0];
        yacc[h][0] = fmaf(qrow[0], l0, yacc[h][0]);
        yacc[h][1] = fmaf(qrow[1], l1, yacc[h][1]);
        yacc[h][2] = fmaf(qrow[2], l2, yacc[h][2]);
        yacc[h][3] = fmaf(qrow[3], l3, yacc[h][3]);
      }
    }
#pragma unroll
    for (int h = 0; h < 4; ++h) {
      float4 r;
      r.x = g1 * yacc[h][0]; r.y = g1 * yacc[h][1];
      r.z = g1 * yacc[h][2]; r.w = g1 * yacc[h][3];
      *(float4*)&out[((size_t)b * 256 + h * 64 + v) * NPIX + n0 + p0] = r;
    }
  }
}

// ---------------- K5 fallback: fused conv+epilogue (known-passing R9) -------
__global__ __launch_bounds__(256, 3) void k_fused(const float* __restrict__ vn,
    const float* __restrict__ q_pre, const float* __restrict__ raw,
    const float* __restrict__ bn_q_w, const float* __restrict__ bn_q_b,
    const float* __restrict__ p, const unsigned short* __restrict__ embA,
    const float* __restrict__ gamma, float* __restrict__ out) {
  __shared__ __align__(16) KMainLDS u;
  __shared__ float lcv[16];
  __shared__ float red[256];
  __shared__ float qsc[64], qsh[64];
  int b = blockIdx.y, v = blockIdx.x, t = threadIdx.x;

  int4* z4 = (int4*)u.imgc;
  for (int l = t; l < 1864; l += 256) z4[l] = make_int4(0, 0, 0, 0);
  if (t < 64) {
    float mean = raw[t] * NINV;
    float var = raw[64 + t] * NINV - mean * mean;
    float sc = rsqrtf(var + EPSBN) * bn_q_w[t];
    qsc[t] = sc;
    qsh[t] = bn_q_b[t] - mean * sc;
  }
  {
    int kk = t & 15, ch = t >> 4;
    const float* pp = p + ((size_t)b * 16 + kk) * NPIX + ch * 64;
    const float* vv = vn + ((size_t)b * 64 + v) * NPIX + ch * 64;
    float part = 0.f;
#pragma unroll 8
    for (int i = 0; i < 64; ++i) part = fmaf(pp[i], vv[i], part);
    red[t] = part;
  }
  __syncthreads();
  if (t < 16) {
    float s = 0.f;
#pragma unroll
    for (int c = 0; c < 16; ++c) s += red[c * 16 + t];
    lcv[t] = s;
  }

  const float* vsrc = vn + ((size_t)b * 64 + v) * NPIX;
  for (int l = t; l < 512; l += 256) {
    int pix = l * 2;
    int y = pix >> 5, xx = pix & 31;
    float2 vv = *(const float2*)(vsrc + pix);
    unsigned short h0 = f2bf(vv.x), h1 = f2bf(vv.y);
#pragma unroll
    for (int s = 0; s < 4; ++s) {
      int base = s * IMG_CS + (y + PADR) * IMG_RS + xx + PADR + s;
      u.imgc[base] = (short)h0;
      u.imgc[base + 1] = (short)h1;
    }
  }
  __syncthreads();

  int lane = t & 63, wv = t >> 6;
  int nl = lane & 15, quad = lane >> 4;
  int y0 = wv * 8;
  int scopy = (4 - (nl & 3)) & 3;
  int colbase = scopy * IMG_CS + nl + quad * 8 + scopy;
  const unsigned short* aptr = embA + nl * 32 + quad * 8;

  floatx4 acc[16];
#pragma unroll
  for (int i = 0; i < 16; ++i) acc[i] = (floatx4){0.f, 0.f, 0.f, 0.f};

  short8v bfrag[8][2];
#pragma unroll
  for (int rr = 0; rr < 8; ++rr) {
    const short* rp = &u.imgc[(y0 + rr) * IMG_RS + colbase];
    bfrag[rr][0] = ld_win(rp);
    bfrag[rr][1] = ld_win(rp + 16);
  }

  short8v a0 = *(const short8v*)aptr;
  short8v a1 = *(const short8v*)(aptr + 512);
#pragma unroll
  for (int dr = 0; dr < RR; ++dr) {
    short8v afrag = a0;
    a0 = a1;
    if (dr < RR - 2) a1 = *(const short8v*)(aptr + (dr + 2) * 512);
#pragma unroll
    for (int rr = 0; rr < 8; ++rr) {
      int slot = (dr + rr) & 7;
      acc[rr * 2 + 0] = __builtin_amdgcn_mfma_f32_16x16x32_bf16(afrag, bfrag[slot][0], acc[rr * 2 + 0], 0, 0, 0);
      acc[rr * 2 + 1] = __builtin_amdgcn_mfma_f32_16x16x32_bf16(afrag, bfrag[slot][1], acc[rr * 2 + 1], 0, 0, 0);
    }
    if (dr < RR - 1) {
      const short* rp = &u.imgc[(y0 + dr + 8) * IMG_RS + colbase];
      int slot = dr & 7;
      bfrag[slot][0] = ld_win(rp);
      bfrag[slot][1] = ld_win(rp + 16);
    }
  }

  __syncthreads();
#pragma unroll
  for (int tt = 0; tt < 16; ++tt) {
    int y = y0 + (tt >> 1), c0 = (tt & 1) << 4;
    int pix = y * 32 + c0 + nl;
#pragma unroll
    for (int r = 0; r < 4; ++r)
      u.lam[(quad * 4 + r) * LAM_RS + pix] = (short)f2bf(acc[tt][r] + lcv[quad * 4 + r]);
  }
  __syncthreads();

  int p0 = t * 4;
  float yacc[4][4];
#pragma unroll
  for (int h = 0; h < 4; ++h)
#pragma unroll
    for (int i = 0; i < 4; ++i) yacc[h][i] = 0.f;
  const float* qb = q_pre + ((size_t)b * 64) * NPIX + p0;
#pragma unroll
  for (int k = 0; k < 16; ++k) {
    uint2 w = *(const uint2*)&u.lam[k * LAM_RS + p0];
    float l0 = bf2f((unsigned short)(w.x & 0xffffu));
    float l1 = bf2f((unsigned short)(w.x >> 16));
    float l2 = bf2f((unsigned short)(w.y & 0xffffu));
    float l3 = bf2f((unsigned short)(w.y >> 16));
#pragma unroll
    for (int h = 0; h < 4; ++h) {
      int o = h * 16 + k;
      float4 qv = *(const float4*)(qb + (size_t)o * NPIX);
      yacc[h][0] = fmaf(fmaf(qv.x, qsc[o], qsh[o]), l0, yacc[h][0]);
      yacc[h][1] = fmaf(fmaf(qv.y, qsc[o], qsh[o]), l1, yacc[h][1]);
      yacc[h][2] = fmaf(fmaf(qv.z, qsc[o], qsh[o]), l2, yacc[h][2]);
      yacc[h][3] = fmaf(fmaf(qv.w, qsc[o], qsh[o]), l3, yacc[h][3]);
    }
  }
  float g1 = 1.0f + gamma[0];
#pragma unroll
  for (int h = 0; h < 4; ++h) {
    float4 r;
    r.x = g1 * yacc[h][0]; r.y = g1 * yacc[h][1];
    r.z = g1 * yacc[h][2]; r.w = g1 * yacc[h][3];
    *(float4*)&out[((size_t)b * 256 + h * 64 + v) * NPIX + p0] = r;
  }
}

extern "C" void kernel_launch(void* const* d_in, const int* in_sizes, int n_in,
                              void* d_out, int out_size, void* d_ws, size_t ws_size,
                              hipStream_t stream) {
  const float* x      = (const float*)d_in[0];
  const float* Wq     = (const float*)d_in[1];
  const float* bn_q_w = (const float*)d_in[2];
  const float* bn_q_b = (const float*)d_in[3];
  const float* Wk     = (const float*)d_in[4];
  const float* Wv     = (const float*)d_in[5];
  const float* bn_v_w = (const float*)d_in[6];
  const float* bn_v_b = (const float*)d_in[7];
  const float* emb    = (const float*)d_in[8];
  const float* gamma  = (const float*)d_in[9];
  float* out = (float*)d_out;

  float* ws    = (float*)d_ws;
  float* q_pre = ws;                                     // B*64*N
  float* k_pre = q_pre + (size_t)BB * 64 * NPIX;         // B*16*N
  float* vn    = k_pre + (size_t)BB * 16 * NPIX;         // B*64*N
  float* p     = vn    + (size_t)BB * 64 * NPIX;         // B*16*N
  float* raw   = p     + (size_t)BB * 16 * NPIX;         // 256 raw BN sums
  unsigned short* embA = (unsigned short*)(raw + 256);   // 23*16*32 ushorts
  unsigned short* wA   = embA + 23 * 16 * 32;            // 144*256 ushorts
  unsigned short* lamG = wA + 144 * 256;                 // B*64*16*N ushorts (64 MB)

  size_t need = ((size_t)(lamG - (unsigned short*)ws)) * 2
              + (size_t)BB * 64 * 16 * NPIX * 2;

  k_prep  <<<dim3(190),       256, 0, stream>>>(emb, embA, Wq, Wk, Wv, wA, raw);
  k_proj  <<<dim3(16, BB),    256, 0, stream>>>(x, wA, q_pre, k_pre, vn, raw);
  k_nvsm  <<<dim3(32, BB),    256, 0, stream>>>(vn, raw, bn_v_w, bn_v_b, k_pre, p);
  if (ws_size >= need) {
    k_conv<<<dim3(64, BB),    256, 0, stream>>>(vn, p, embA, lamG);
    k_epi2<<<dim3(16, BB, 2), 256, 0, stream>>>(lamG, q_pre, raw, bn_q_w, bn_q_b, gamma, out);
  } else {
    k_fused<<<dim3(64, BB),   256, 0, stream>>>(vn, q_pre, raw, bn_q_w, bn_q_b, p, embA, gamma, out);
  }
}